// Round 10
// baseline (220.891 us; speedup 1.0000x reference)
//
#include <hip/hip_runtime.h>

#define THREADS 256
#define BNODES 256           // nodes per dst-bucket
#define PACK_SHIFT 20        // src in low 20 bits, local dst in bits 20..27
#define TILE 2048            // edges per block in count/scatter

__device__ __forceinline__ unsigned short f2bf(float f) {
    unsigned u = __float_as_uint(f);
    unsigned r = (u + 0x7fff + ((u >> 16) & 1)) >> 16;  // RNE
    return (unsigned short)r;
}
__device__ __forceinline__ float bf2f_lo(unsigned v) { return __uint_as_float(v << 16); }
__device__ __forceinline__ float bf2f_hi(unsigned v) { return __uint_as_float(v & 0xffff0000u); }

// ---------------- CSR build: block-binned counting sort, no per-edge global atomics ----

__global__ void zero2_kernel(int* __restrict__ a, int* __restrict__ b, int n) {
    for (int i = threadIdx.x; i < n; i += 1024) { a[i] = 0; b[i] = 0; }
}

__global__ __launch_bounds__(256) void count_buckets(const int* __restrict__ dst,
                                                     int* __restrict__ subcnt,
                                                     int NB, int E) {
    __shared__ int h[1024];
    int t = threadIdx.x;
    for (int i = t; i < NB; i += 256) h[i] = 0;
    __syncthreads();
    int e0 = blockIdx.x * TILE;
    int e1 = min(e0 + TILE, E);
    for (int e = e0 + t; e < e1; e += 256)
        atomicAdd(&h[dst[e] >> 8], 1);
    __syncthreads();
    for (int i = t; i < NB; i += 256)
        if (h[i] > 0) atomicAdd(&subcnt[i], h[i]);
}

__global__ void scan_small_kernel(const int* __restrict__ cnt, int* __restrict__ ptr,
                                  int nb, int total) {
    __shared__ int sh[1024];
    int t = threadIdx.x;
    int v = (t < nb) ? cnt[t] : 0;
    sh[t] = v;
    __syncthreads();
    for (int off = 1; off < 1024; off <<= 1) {
        int add = (t >= off) ? sh[t - off] : 0;
        __syncthreads();
        sh[t] += add;
        __syncthreads();
    }
    if (t < nb) ptr[t] = sh[t] - v;
    if (t == 0) ptr[nb] = total;
}

__global__ __launch_bounds__(256) void block_scatter(const int* __restrict__ src,
                                                     const int* __restrict__ dst,
                                                     const int* __restrict__ subptr,
                                                     int* __restrict__ subcur,
                                                     int* __restrict__ ebuf,
                                                     int NB, int E) {
    __shared__ int h[1024];
    __shared__ int bb[1024];
    int t = threadIdx.x;
    for (int i = t; i < NB; i += 256) h[i] = 0;
    __syncthreads();
    int e0 = blockIdx.x * TILE;
    int e1 = min(e0 + TILE, E);
    for (int e = e0 + t; e < e1; e += 256)
        atomicAdd(&h[dst[e] >> 8], 1);
    __syncthreads();
    for (int i = t; i < NB; i += 256) {
        int c = h[i];
        bb[i] = (c > 0) ? (subptr[i] + atomicAdd(&subcur[i], c)) : 0;
        h[i] = 0;  // reuse as cursor
    }
    __syncthreads();
    for (int e = e0 + t; e < e1; e += 256) {
        int d = dst[e];
        int b = d >> 8;
        int pos = bb[b] + atomicAdd(&h[b], 1);
        ebuf[pos] = src[e] | ((d & (BNODES - 1)) << PACK_SHIFT);
    }
}

__global__ __launch_bounds__(256) void bin_fill_kernel(const int* __restrict__ ebuf,
                                                       const int* __restrict__ subptr,
                                                       int* __restrict__ rowptr,
                                                       float* __restrict__ dis,
                                                       int* __restrict__ srcs,
                                                       int NB, int N, int E) {
    __shared__ int cntL[BNODES];
    __shared__ int rb[BNODES];
    int b = blockIdx.x;
    int t = threadIdx.x;
    int base = b * BNODES;
    int s0 = subptr[b], s1 = subptr[b + 1];
    cntL[t] = 0;
    __syncthreads();
    for (int i = s0 + t; i < s1; i += 256)
        atomicAdd(&cntL[((unsigned)ebuf[i]) >> PACK_SHIFT], 1);
    __syncthreads();
    int myc = cntL[t];
    if (base + t < N) dis[base + t] = rsqrtf((float)myc + 1.0f);
    rb[t] = myc;
    __syncthreads();
    #pragma unroll
    for (int off = 1; off < 256; off <<= 1) {
        int add = (t >= off) ? rb[t - off] : 0;
        __syncthreads();
        rb[t] += add;
        __syncthreads();
    }
    int excl = rb[t] - myc;
    rb[t] = s0 + excl;
    if (base + t < N) rowptr[base + t] = s0 + excl;
    if (b == NB - 1 && t == 0) rowptr[N] = E;
    cntL[t] = 0;  // reuse as cursor
    __syncthreads();
    const int mask = (1 << PACK_SHIFT) - 1;
    for (int i = s0 + t; i < s1; i += 256) {
        int w = ebuf[i];
        int local = ((unsigned)w) >> PACK_SHIFT;
        int pos = rb[local] + atomicAdd(&cntL[local], 1);
        srcs[pos] = w & mask;
    }
}

// ---------------- tiled GEMM ----------------
// Y[M,64] = X[M,K] @ W[K,64], optional row-scale by dis[row].
template<int K, bool SCALE, typename YT>
__global__ __launch_bounds__(256, 4) void gemm_tiled(const float* __restrict__ X,
                                                     const float* __restrict__ W,
                                                     const float* __restrict__ dis,
                                                     YT* __restrict__ Y, int M) {
    __shared__ float Ws[32 * 64];   // current K-chunk of W
    __shared__ float Xs[32 * 68];   // transposed X chunk [k][row], pitch 68
    const int t = threadIdx.x;

    const int r0 = blockIdx.x * 64;
    const int wave = t >> 6;
    const int lane = t & 63;
    const int tr = lane & 15;
    const int tc = (lane >> 4) + wave * 4;

    float acc[4][4] = {};

    #pragma unroll 1
    for (int kc = 0; kc < K; kc += 32) {
        __syncthreads();
        #pragma unroll
        for (int it = 0; it < 2; ++it) {
            int i = it * 256 + t;
            ((float4*)Ws)[i] = ((const float4*)(W + (size_t)kc * 64))[i];
        }
        #pragma unroll
        for (int it = 0; it < 2; ++it) {
            int i = it * 256 + t;
            int row = i & 63;
            int kq = i >> 6;           // 0..7
            int gr = r0 + row;
            if (gr >= M) gr = M - 1;
            float4 v = *(const float4*)(X + (size_t)gr * K + kc + kq * 4);
            Xs[(kq * 4 + 0) * 68 + row] = v.x;
            Xs[(kq * 4 + 1) * 68 + row] = v.y;
            Xs[(kq * 4 + 2) * 68 + row] = v.z;
            Xs[(kq * 4 + 3) * 68 + row] = v.w;
        }
        __syncthreads();
        #pragma unroll
        for (int kk = 0; kk < 32; ++kk) {
            float4 xv = *(const float4*)(Xs + kk * 68 + tr * 4);
            float4 wv = *(const float4*)(Ws + kk * 64 + tc * 4);
            acc[0][0] = fmaf(xv.x, wv.x, acc[0][0]);
            acc[0][1] = fmaf(xv.x, wv.y, acc[0][1]);
            acc[0][2] = fmaf(xv.x, wv.z, acc[0][2]);
            acc[0][3] = fmaf(xv.x, wv.w, acc[0][3]);
            acc[1][0] = fmaf(xv.y, wv.x, acc[1][0]);
            acc[1][1] = fmaf(xv.y, wv.y, acc[1][1]);
            acc[1][2] = fmaf(xv.y, wv.z, acc[1][2]);
            acc[1][3] = fmaf(xv.y, wv.w, acc[1][3]);
            acc[2][0] = fmaf(xv.z, wv.x, acc[2][0]);
            acc[2][1] = fmaf(xv.z, wv.y, acc[2][1]);
            acc[2][2] = fmaf(xv.z, wv.z, acc[2][2]);
            acc[2][3] = fmaf(xv.z, wv.w, acc[2][3]);
            acc[3][0] = fmaf(xv.w, wv.x, acc[3][0]);
            acc[3][1] = fmaf(xv.w, wv.y, acc[3][1]);
            acc[3][2] = fmaf(xv.w, wv.z, acc[3][2]);
            acc[3][3] = fmaf(xv.w, wv.w, acc[3][3]);
        }
    }

    #pragma unroll
    for (int i = 0; i < 4; ++i) {
        int row = r0 + tr * 4 + i;
        if (row < M) {
            float s = SCALE ? dis[row] : 1.0f;
            if constexpr (sizeof(YT) == 2) {
                ushort4 st;
                st.x = f2bf(acc[i][0] * s);
                st.y = f2bf(acc[i][1] * s);
                st.z = f2bf(acc[i][2] * s);
                st.w = f2bf(acc[i][3] * s);
                *(ushort4*)((unsigned short*)Y + (size_t)row * 64 + tc * 4) = st;
            } else {
                float4 st = make_float4(acc[i][0] * s, acc[i][1] * s,
                                        acc[i][2] * s, acc[i][3] * s);
                *(float4*)((float*)Y + (size_t)row * 64 + tc * 4) = st;
            }
        }
    }
}

// ---------------- pull aggregate: 2 nodes per wave (32-lane halves), bf16x2 loads ----
// Unmasked unroll-8 main loop; half-wave divergence handled by exec mask.
template<bool HEAD>
__global__ __launch_bounds__(256) void pull2_kernel(const unsigned* __restrict__ hpre2,
                                                    const int* __restrict__ rowptr,
                                                    const int* __restrict__ srcs,
                                                    const float* __restrict__ dis,
                                                    const float* __restrict__ b,
                                                    const float* __restrict__ Wh,
                                                    float* __restrict__ out,
                                                    float2* __restrict__ s01, int N) {
    int tid = threadIdx.x;
    int wave = tid >> 6;
    int lane = tid & 63;
    int l = lane & 31;                       // feature-pair index: features 2l, 2l+1
    int node = blockIdx.x * 8 + wave * 2 + (lane >> 5);
    bool valid = node < N;
    int nc = valid ? node : N - 1;
    int i = rowptr[nc];
    int end = valid ? rowptr[nc + 1] : i;

    unsigned sv = hpre2[(size_t)nc * 32 + l];   // self loop
    float accx = bf2f_lo(sv), accy = bf2f_hi(sv);

    int e8 = end - ((end - i) & 7);
    for (; i < e8; i += 8) {
        #pragma unroll
        for (int k = 0; k < 8; ++k) {
            int s = srcs[i + k];
            unsigned v = hpre2[(size_t)s * 32 + l];
            accx += bf2f_lo(v);
            accy += bf2f_hi(v);
        }
    }
    for (; i < end; ++i) {
        int s = srcs[i];
        unsigned v = hpre2[(size_t)s * 32 + l];
        accx += bf2f_lo(v);
        accy += bf2f_hi(v);
    }

    float d = dis[nc];
    float2 bb = ((const float2*)b)[l];
    float ox = accx * d + bb.x;
    float oy = accy * d + bb.y;
    ox = ox > 0.f ? ox : 0.f;
    oy = oy > 0.f ? oy : 0.f;

    if (HEAD) {
        float2 w0 = ((const float2*)Wh)[l];
        float2 w1 = ((const float2*)(Wh + 64))[l];
        float p0 = ox * w0.x + oy * w0.y;
        float p1 = ox * w1.x + oy * w1.y;
        #pragma unroll
        for (int off = 16; off > 0; off >>= 1) {
            p0 += __shfl_down(p0, off, 32);
            p1 += __shfl_down(p1, off, 32);
        }
        if (valid && l == 0) s01[node] = make_float2(p0, p1);
    } else {
        if (valid) *(float2*)(out + (size_t)node * 64 + 2 * l) = make_float2(ox, oy);
    }
}

// out[p] = s01[p0].x + s01[p1].y + bh  (s01 is ~800KB -> L2-resident gathers)
__global__ void pair_kernel(const float2* __restrict__ s01, const int* __restrict__ pairs,
                            const float* __restrict__ bh, float* __restrict__ out, int P) {
    int p = blockIdx.x * blockDim.x + threadIdx.x;
    if (p < P) {
        int p0 = pairs[2 * (size_t)p];
        int p1 = pairs[2 * (size_t)p + 1];
        out[p] = s01[p0].x + s01[p1].y + bh[0];
    }
}

// ---------------- fallback (atomic push, full fp32) ----------------
__global__ void degf_kernel(const int* __restrict__ dst, float* __restrict__ deg, int E) {
    int e = blockIdx.x * blockDim.x + threadIdx.x;
    if (e < E) atomicAdd(&deg[dst[e]], 1.0f);
}
__global__ void rsqrtf_kernel(float* deg, int N) {
    int i = blockIdx.x * blockDim.x + threadIdx.x;
    if (i < N) deg[i] = rsqrtf(deg[i] + 1.0f);
}
__global__ void scatter_kernel(const float* __restrict__ h, const int* __restrict__ src,
                               const int* __restrict__ dst, const float* __restrict__ dis,
                               float* __restrict__ agg, int E, int N) {
    long long idx = (long long)blockIdx.x * blockDim.x + threadIdx.x;
    int e = (int)(idx >> 6);
    int f = (int)(idx & 63);
    if (e >= E + N) return;
    int s, d;
    if (e < E) { s = src[e]; d = dst[e]; } else { s = e - E; d = s; }
    float norm = dis[s] * dis[d];
    atomicAdd(&agg[(size_t)d * 64 + f], h[(size_t)s * 64 + f] * norm);
}
__global__ void bias_relu_kernel(float* __restrict__ buf, const float* __restrict__ b,
                                 long long total) {
    long long i = (long long)blockIdx.x * blockDim.x + threadIdx.x;
    if (i < total) {
        float v = buf[i] + b[(int)(i & 63)];
        buf[i] = v > 0.f ? v : 0.f;
    }
}
__global__ void head_kernel(const float* __restrict__ h, const int* __restrict__ pairs,
                            const float* __restrict__ Wh, const float* __restrict__ bh,
                            float* __restrict__ out, int P) {
    long long idx = (long long)blockIdx.x * blockDim.x + threadIdx.x;
    int p = (int)(idx >> 6);
    int lane = threadIdx.x & 63;
    if (p >= P) return;
    int p0 = pairs[2 * (size_t)p];
    int p1 = pairs[2 * (size_t)p + 1];
    float v = h[(size_t)p0 * 64 + lane] * Wh[lane]
            + h[(size_t)p1 * 64 + lane] * Wh[64 + lane];
    #pragma unroll
    for (int off = 32; off > 0; off >>= 1) v += __shfl_down(v, off);
    if (lane == 0) out[p] = v + bh[0];
}

extern "C" void kernel_launch(void* const* d_in, const int* in_sizes, int n_in,
                              void* d_out, int out_size, void* d_ws, size_t ws_size,
                              hipStream_t stream) {
    const float* x     = (const float*)d_in[0];
    const int*   ei    = (const int*)d_in[1];   // [2,E]: row0=src, row1=dst
    const int*   pairs = (const int*)d_in[3];   // [P,2]
    const float* W1    = (const float*)d_in[4];
    const float* b1    = (const float*)d_in[5];
    const float* W2    = (const float*)d_in[6];
    const float* b2    = (const float*)d_in[7];
    const float* Wh    = (const float*)d_in[8];
    const float* bh    = (const float*)d_in[9];

    const int N = in_sizes[0] / 128;
    const int E = in_sizes[1] / 2;
    const int P = in_sizes[3] / 2;
    const int* srcArr = ei;
    const int* dstArr = ei + E;

    const size_t feat_total = (size_t)N * 64;
    const int NB = (N + BNODES - 1) / BNODES;      // dst buckets
    const int tileBlocks = (E + TILE - 1) / TILE;  // edge tiles
    const int gemm_blocks = (N + 63) / 64;
    const int pull_blocks = (N + 7) / 8;

    auto align512 = [](size_t v) { return (v + 511) & ~(size_t)511; };

    char* ws = (char*)d_ws;
    size_t off = 0;
    float*  dis    = (float*) (ws + off); off += align512((size_t)N * 4);
    int*    rowptr = (int*)   (ws + off); off += align512(((size_t)N + 1) * 4);
    int*    subcnt = (int*)   (ws + off); off += align512((size_t)NB * 4);
    int*    subcur = (int*)   (ws + off); off += align512((size_t)NB * 4);
    int*    subptr = (int*)   (ws + off); off += align512(((size_t)NB + 1) * 4);
    float2* s01    = (float2*)(ws + off); off += align512((size_t)N * 8);
    int*    srcs   = (int*)   (ws + off); off += align512((size_t)E * 4);
    // bufA slot holds: ebuf (E ints) early, then bf16 hpre [N][64]; sized for max.
    size_t bufA_bytes = align512((size_t)E * 4 > feat_total * 2 ? (size_t)E * 4
                                                                : feat_total * 2);
    unsigned short* bufA = (unsigned short*)(ws + off); off += bufA_bytes;
    float*  bufB   = (float*) (ws + off); off += align512(feat_total * 4);
    int*    ebuf   = (int*)bufA;  // aliased: consumed by bin_fill before gemm1 writes bufA
    const bool csr_ok = (off <= ws_size) && (NB <= 1024) && (N <= (1 << PACK_SHIFT));

    if (csr_ok) {
        // ---- CSR build ----
        zero2_kernel<<<1, 1024, 0, stream>>>(subcnt, subcur, NB);
        count_buckets<<<tileBlocks, 256, 0, stream>>>(dstArr, subcnt, NB, E);
        scan_small_kernel<<<1, 1024, 0, stream>>>(subcnt, subptr, NB, E);
        block_scatter<<<tileBlocks, 256, 0, stream>>>(srcArr, dstArr, subptr, subcur,
                                                      ebuf, NB, E);
        bin_fill_kernel<<<NB, 256, 0, stream>>>(ebuf, subptr, rowptr, dis, srcs, NB, N, E);

        // ---- layer 1: hpre(bf16) = (x@W1)*dis ; bufB(fp32) = relu(...) ----
        gemm_tiled<128, true, unsigned short><<<gemm_blocks, THREADS, 0, stream>>>(
            x, W1, dis, bufA, N);
        pull2_kernel<false><<<pull_blocks, THREADS, 0, stream>>>(
            (const unsigned*)bufA, rowptr, srcs, dis, b1, nullptr, bufB, nullptr, N);

        // ---- layer 2 + head dots fused ----
        gemm_tiled<64, true, unsigned short><<<gemm_blocks, THREADS, 0, stream>>>(
            bufB, W2, dis, bufA, N);
        pull2_kernel<true><<<pull_blocks, THREADS, 0, stream>>>(
            (const unsigned*)bufA, rowptr, srcs, dis, b2, Wh, nullptr, s01, N);

        // ---- pair gather ----
        pair_kernel<<<(P + THREADS - 1) / THREADS, THREADS, 0, stream>>>(
            s01, pairs, bh, (float*)d_out, P);
    } else {
        // ---- fallback: atomic push path, fp32 ----
        size_t o2 = 0;
        float* deg  = (float*)(ws + o2); o2 += align512((size_t)N * 4);
        float* bA   = (float*)(ws + o2); o2 += align512(feat_total * 4);
        float* bB   = (float*)(ws + o2);
        const size_t edge_threads = (size_t)(E + N) * 64;
        const int eblocks = (E + THREADS - 1) / THREADS;

        hipMemsetAsync(deg, 0, (size_t)N * 4, stream);
        degf_kernel<<<eblocks, THREADS, 0, stream>>>(dstArr, deg, E);
        rsqrtf_kernel<<<(N + THREADS - 1) / THREADS, THREADS, 0, stream>>>(deg, N);

        gemm_tiled<128, false, float><<<gemm_blocks, THREADS, 0, stream>>>(x, W1, deg, bA, N);
        hipMemsetAsync(bB, 0, feat_total * 4, stream);
        scatter_kernel<<<(unsigned)((edge_threads + THREADS - 1) / THREADS), THREADS, 0, stream>>>(
            bA, srcArr, dstArr, deg, bB, E, N);
        bias_relu_kernel<<<(unsigned)((feat_total + THREADS - 1) / THREADS), THREADS, 0, stream>>>(
            bB, b1, (long long)feat_total);

        gemm_tiled<64, false, float><<<gemm_blocks, THREADS, 0, stream>>>(bB, W2, deg, bA, N);
        hipMemsetAsync(bB, 0, feat_total * 4, stream);
        scatter_kernel<<<(unsigned)((edge_threads + THREADS - 1) / THREADS), THREADS, 0, stream>>>(
            bA, srcArr, dstArr, deg, bB, E, N);
        bias_relu_kernel<<<(unsigned)((feat_total + THREADS - 1) / THREADS), THREADS, 0, stream>>>(
            bB, b2, (long long)feat_total);

        head_kernel<<<(unsigned)(((size_t)P * 64 + THREADS - 1) / THREADS), THREADS, 0, stream>>>(
            bB, pairs, Wh, bh, (float*)d_out, P);
    }
}

// Round 11
// 200.353 us; speedup vs baseline: 1.1025x; 1.1025x over previous
//
#include <hip/hip_runtime.h>

#define THREADS 256
#define BNODES 256           // nodes per dst-bucket
#define PACK_SHIFT 20        // src in low 20 bits, local dst in bits 20..27
#define TILE 2048            // edges per block in count/scatter

__device__ __forceinline__ unsigned short f2bf(float f) {
    unsigned u = __float_as_uint(f);
    unsigned r = (u + 0x7fff + ((u >> 16) & 1)) >> 16;  // RNE
    return (unsigned short)r;
}
__device__ __forceinline__ float bf2f_lo(unsigned v) { return __uint_as_float(v << 16); }
__device__ __forceinline__ float bf2f_hi(unsigned v) { return __uint_as_float(v & 0xffff0000u); }

// ---------------- CSR build: block-binned counting sort, no per-edge global atomics ----

__global__ void zero2_kernel(int* __restrict__ a, int* __restrict__ b, int n) {
    for (int i = threadIdx.x; i < n; i += 1024) { a[i] = 0; b[i] = 0; }
}

__global__ __launch_bounds__(256) void count_buckets(const int* __restrict__ dst,
                                                     int* __restrict__ subcnt,
                                                     int NB, int E) {
    __shared__ int h[1024];
    int t = threadIdx.x;
    for (int i = t; i < NB; i += 256) h[i] = 0;
    __syncthreads();
    int e0 = blockIdx.x * TILE;
    int e1 = min(e0 + TILE, E);
    for (int e = e0 + t; e < e1; e += 256)
        atomicAdd(&h[dst[e] >> 8], 1);
    __syncthreads();
    for (int i = t; i < NB; i += 256)
        if (h[i] > 0) atomicAdd(&subcnt[i], h[i]);
}

__global__ void scan_small_kernel(const int* __restrict__ cnt, int* __restrict__ ptr,
                                  int nb, int total) {
    __shared__ int sh[1024];
    int t = threadIdx.x;
    int v = (t < nb) ? cnt[t] : 0;
    sh[t] = v;
    __syncthreads();
    for (int off = 1; off < 1024; off <<= 1) {
        int add = (t >= off) ? sh[t - off] : 0;
        __syncthreads();
        sh[t] += add;
        __syncthreads();
    }
    if (t < nb) ptr[t] = sh[t] - v;
    if (t == 0) ptr[nb] = total;
}

__global__ __launch_bounds__(256) void block_scatter(const int* __restrict__ src,
                                                     const int* __restrict__ dst,
                                                     const int* __restrict__ subptr,
                                                     int* __restrict__ subcur,
                                                     int* __restrict__ ebuf,
                                                     int NB, int E) {
    __shared__ int h[1024];
    __shared__ int bb[1024];
    int t = threadIdx.x;
    for (int i = t; i < NB; i += 256) h[i] = 0;
    __syncthreads();
    int e0 = blockIdx.x * TILE;
    int e1 = min(e0 + TILE, E);
    for (int e = e0 + t; e < e1; e += 256)
        atomicAdd(&h[dst[e] >> 8], 1);
    __syncthreads();
    for (int i = t; i < NB; i += 256) {
        int c = h[i];
        bb[i] = (c > 0) ? (subptr[i] + atomicAdd(&subcur[i], c)) : 0;
        h[i] = 0;  // reuse as cursor
    }
    __syncthreads();
    for (int e = e0 + t; e < e1; e += 256) {
        int d = dst[e];
        int b = d >> 8;
        int pos = bb[b] + atomicAdd(&h[b], 1);
        ebuf[pos] = src[e] | ((d & (BNODES - 1)) << PACK_SHIFT);
    }
}

__global__ __launch_bounds__(256) void bin_fill_kernel(const int* __restrict__ ebuf,
                                                       const int* __restrict__ subptr,
                                                       int* __restrict__ rowptr,
                                                       float* __restrict__ dis,
                                                       int* __restrict__ srcs,
                                                       int NB, int N, int E) {
    __shared__ int cntL[BNODES];
    __shared__ int rb[BNODES];
    int b = blockIdx.x;
    int t = threadIdx.x;
    int base = b * BNODES;
    int s0 = subptr[b], s1 = subptr[b + 1];
    cntL[t] = 0;
    __syncthreads();
    for (int i = s0 + t; i < s1; i += 256)
        atomicAdd(&cntL[((unsigned)ebuf[i]) >> PACK_SHIFT], 1);
    __syncthreads();
    int myc = cntL[t];
    if (base + t < N) dis[base + t] = rsqrtf((float)myc + 1.0f);
    rb[t] = myc;
    __syncthreads();
    #pragma unroll
    for (int off = 1; off < 256; off <<= 1) {
        int add = (t >= off) ? rb[t - off] : 0;
        __syncthreads();
        rb[t] += add;
        __syncthreads();
    }
    int excl = rb[t] - myc;
    rb[t] = s0 + excl;
    if (base + t < N) rowptr[base + t] = s0 + excl;
    if (b == NB - 1 && t == 0) rowptr[N] = E;
    cntL[t] = 0;  // reuse as cursor
    __syncthreads();
    const int mask = (1 << PACK_SHIFT) - 1;
    for (int i = s0 + t; i < s1; i += 256) {
        int w = ebuf[i];
        int local = ((unsigned)w) >> PACK_SHIFT;
        int pos = rb[local] + atomicAdd(&cntL[local], 1);
        srcs[pos] = w & mask;
    }
}

// ---------------- tiled GEMM ----------------
template<int K, bool SCALE, typename YT>
__global__ __launch_bounds__(256, 4) void gemm_tiled(const float* __restrict__ X,
                                                     const float* __restrict__ W,
                                                     const float* __restrict__ dis,
                                                     YT* __restrict__ Y, int M) {
    __shared__ float Ws[32 * 64];   // current K-chunk of W
    __shared__ float Xs[32 * 68];   // transposed X chunk [k][row], pitch 68
    const int t = threadIdx.x;

    const int r0 = blockIdx.x * 64;
    const int wave = t >> 6;
    const int lane = t & 63;
    const int tr = lane & 15;
    const int tc = (lane >> 4) + wave * 4;

    float acc[4][4] = {};

    #pragma unroll 1
    for (int kc = 0; kc < K; kc += 32) {
        __syncthreads();
        #pragma unroll
        for (int it = 0; it < 2; ++it) {
            int i = it * 256 + t;
            ((float4*)Ws)[i] = ((const float4*)(W + (size_t)kc * 64))[i];
        }
        #pragma unroll
        for (int it = 0; it < 2; ++it) {
            int i = it * 256 + t;
            int row = i & 63;
            int kq = i >> 6;           // 0..7
            int gr = r0 + row;
            if (gr >= M) gr = M - 1;
            float4 v = *(const float4*)(X + (size_t)gr * K + kc + kq * 4);
            Xs[(kq * 4 + 0) * 68 + row] = v.x;
            Xs[(kq * 4 + 1) * 68 + row] = v.y;
            Xs[(kq * 4 + 2) * 68 + row] = v.z;
            Xs[(kq * 4 + 3) * 68 + row] = v.w;
        }
        __syncthreads();
        #pragma unroll
        for (int kk = 0; kk < 32; ++kk) {
            float4 xv = *(const float4*)(Xs + kk * 68 + tr * 4);
            float4 wv = *(const float4*)(Ws + kk * 64 + tc * 4);
            acc[0][0] = fmaf(xv.x, wv.x, acc[0][0]);
            acc[0][1] = fmaf(xv.x, wv.y, acc[0][1]);
            acc[0][2] = fmaf(xv.x, wv.z, acc[0][2]);
            acc[0][3] = fmaf(xv.x, wv.w, acc[0][3]);
            acc[1][0] = fmaf(xv.y, wv.x, acc[1][0]);
            acc[1][1] = fmaf(xv.y, wv.y, acc[1][1]);
            acc[1][2] = fmaf(xv.y, wv.z, acc[1][2]);
            acc[1][3] = fmaf(xv.y, wv.w, acc[1][3]);
            acc[2][0] = fmaf(xv.z, wv.x, acc[2][0]);
            acc[2][1] = fmaf(xv.z, wv.y, acc[2][1]);
            acc[2][2] = fmaf(xv.z, wv.z, acc[2][2]);
            acc[2][3] = fmaf(xv.z, wv.w, acc[2][3]);
            acc[3][0] = fmaf(xv.w, wv.x, acc[3][0]);
            acc[3][1] = fmaf(xv.w, wv.y, acc[3][1]);
            acc[3][2] = fmaf(xv.w, wv.z, acc[3][2]);
            acc[3][3] = fmaf(xv.w, wv.w, acc[3][3]);
        }
    }

    #pragma unroll
    for (int i = 0; i < 4; ++i) {
        int row = r0 + tr * 4 + i;
        if (row < M) {
            float s = SCALE ? dis[row] : 1.0f;
            if constexpr (sizeof(YT) == 2) {
                ushort4 st;
                st.x = f2bf(acc[i][0] * s);
                st.y = f2bf(acc[i][1] * s);
                st.z = f2bf(acc[i][2] * s);
                st.w = f2bf(acc[i][3] * s);
                *(ushort4*)((unsigned short*)Y + (size_t)row * 64 + tc * 4) = st;
            } else {
                float4 st = make_float4(acc[i][0] * s, acc[i][1] * s,
                                        acc[i][2] * s, acc[i][3] * s);
                *(float4*)((float*)Y + (size_t)row * 64 + tc * 4) = st;
            }
        }
    }
}

// ---------------- pull aggregate ----------------
// 2 nodes/wave; per node: 16 lanes x uint2 (4 bf16 feats) x 2 edge-slots.
// Lock-step masked loop (uniform trip via __any); eo partials combined pre-ReLU.
template<bool HEAD>
__global__ __launch_bounds__(256) void pull2_kernel(const unsigned* __restrict__ hpre2,
                                                    const int* __restrict__ rowptr,
                                                    const int* __restrict__ srcs,
                                                    const float* __restrict__ dis,
                                                    const float* __restrict__ b,
                                                    const float* __restrict__ Wh,
                                                    float* __restrict__ out,
                                                    float2* __restrict__ s01, int N) {
    int tid = threadIdx.x;
    int lane = tid & 63;
    int half = lane >> 5;          // which node of the wave's pair
    int sub = lane & 31;
    int eo = sub >> 4;             // edge slot 0/1
    int l = sub & 15;              // feature quad: uints 2l,2l+1 = feats 4l..4l+3
    int node = blockIdx.x * 8 + (tid >> 6) * 2 + half;
    bool valid = node < N;
    int nc = valid ? node : N - 1;
    int i0 = rowptr[nc];
    int end = valid ? rowptr[nc + 1] : i0;

    // self loop counted once (eo==0 lanes)
    uint2 sv = *(const uint2*)(hpre2 + (size_t)nc * 32 + 2 * l);
    float a0 = eo ? 0.f : bf2f_lo(sv.x);
    float a1 = eo ? 0.f : bf2f_hi(sv.x);
    float a2 = eo ? 0.f : bf2f_lo(sv.y);
    float a3 = eo ? 0.f : bf2f_hi(sv.y);

    int i = i0 + eo;
    while (__any(i < end)) {
        #pragma unroll
        for (int k = 0; k < 4; ++k) {        // 4 steps x 2 slots = 8 edges/node/iter
            int idx = i + 2 * k;
            bool m = idx < end;
            int s = srcs[m ? idx : 0];       // clamp to edge 0 (row cache-hot)
            uint2 v = *(const uint2*)(hpre2 + (size_t)s * 32 + 2 * l);
            a0 += m ? bf2f_lo(v.x) : 0.f;
            a1 += m ? bf2f_hi(v.x) : 0.f;
            a2 += m ? bf2f_lo(v.y) : 0.f;
            a3 += m ? bf2f_hi(v.y) : 0.f;
        }
        i += 8;
    }

    // combine the two edge-slot partials (lanes eo==0 get totals)
    a0 += __shfl_down(a0, 16, 32);
    a1 += __shfl_down(a1, 16, 32);
    a2 += __shfl_down(a2, 16, 32);
    a3 += __shfl_down(a3, 16, 32);

    float d = dis[nc];
    float4 bb = ((const float4*)b)[l];
    float o0 = fmaf(a0, d, bb.x);
    float o1 = fmaf(a1, d, bb.y);
    float o2 = fmaf(a2, d, bb.z);
    float o3 = fmaf(a3, d, bb.w);
    o0 = o0 > 0.f ? o0 : 0.f;
    o1 = o1 > 0.f ? o1 : 0.f;
    o2 = o2 > 0.f ? o2 : 0.f;
    o3 = o3 > 0.f ? o3 : 0.f;

    if (HEAD) {
        float4 w0 = ((const float4*)Wh)[l];
        float4 w1 = ((const float4*)(Wh + 64))[l];
        float p0 = o0 * w0.x + o1 * w0.y + o2 * w0.z + o3 * w0.w;
        float p1 = o0 * w1.x + o1 * w1.y + o2 * w1.z + o3 * w1.w;
        #pragma unroll
        for (int off = 8; off > 0; off >>= 1) {
            p0 += __shfl_down(p0, off, 16);
            p1 += __shfl_down(p1, off, 16);
        }
        if (valid && sub == 0) s01[node] = make_float2(p0, p1);
    } else {
        if (valid && eo == 0)
            *(float4*)(out + (size_t)node * 64 + 4 * l) = make_float4(o0, o1, o2, o3);
    }
}

// out[p] = s01[p0].x + s01[p1].y + bh  (s01 is ~800KB -> L2-resident gathers)
__global__ void pair_kernel(const float2* __restrict__ s01, const int* __restrict__ pairs,
                            const float* __restrict__ bh, float* __restrict__ out, int P) {
    int p = blockIdx.x * blockDim.x + threadIdx.x;
    if (p < P) {
        int p0 = pairs[2 * (size_t)p];
        int p1 = pairs[2 * (size_t)p + 1];
        out[p] = s01[p0].x + s01[p1].y + bh[0];
    }
}

// ---------------- fallback (atomic push, full fp32) ----------------
__global__ void degf_kernel(const int* __restrict__ dst, float* __restrict__ deg, int E) {
    int e = blockIdx.x * blockDim.x + threadIdx.x;
    if (e < E) atomicAdd(&deg[dst[e]], 1.0f);
}
__global__ void rsqrtf_kernel(float* deg, int N) {
    int i = blockIdx.x * blockDim.x + threadIdx.x;
    if (i < N) deg[i] = rsqrtf(deg[i] + 1.0f);
}
__global__ void scatter_kernel(const float* __restrict__ h, const int* __restrict__ src,
                               const int* __restrict__ dst, const float* __restrict__ dis,
                               float* __restrict__ agg, int E, int N) {
    long long idx = (long long)blockIdx.x * blockDim.x + threadIdx.x;
    int e = (int)(idx >> 6);
    int f = (int)(idx & 63);
    if (e >= E + N) return;
    int s, d;
    if (e < E) { s = src[e]; d = dst[e]; } else { s = e - E; d = s; }
    float norm = dis[s] * dis[d];
    atomicAdd(&agg[(size_t)d * 64 + f], h[(size_t)s * 64 + f] * norm);
}
__global__ void bias_relu_kernel(float* __restrict__ buf, const float* __restrict__ b,
                                 long long total) {
    long long i = (long long)blockIdx.x * blockDim.x + threadIdx.x;
    if (i < total) {
        float v = buf[i] + b[(int)(i & 63)];
        buf[i] = v > 0.f ? v : 0.f;
    }
}
__global__ void head_kernel(const float* __restrict__ h, const int* __restrict__ pairs,
                            const float* __restrict__ Wh, const float* __restrict__ bh,
                            float* __restrict__ out, int P) {
    long long idx = (long long)blockIdx.x * blockDim.x + threadIdx.x;
    int p = (int)(idx >> 6);
    int lane = threadIdx.x & 63;
    if (p >= P) return;
    int p0 = pairs[2 * (size_t)p];
    int p1 = pairs[2 * (size_t)p + 1];
    float v = h[(size_t)p0 * 64 + lane] * Wh[lane]
            + h[(size_t)p1 * 64 + lane] * Wh[64 + lane];
    #pragma unroll
    for (int off = 32; off > 0; off >>= 1) v += __shfl_down(v, off);
    if (lane == 0) out[p] = v + bh[0];
}

extern "C" void kernel_launch(void* const* d_in, const int* in_sizes, int n_in,
                              void* d_out, int out_size, void* d_ws, size_t ws_size,
                              hipStream_t stream) {
    const float* x     = (const float*)d_in[0];
    const int*   ei    = (const int*)d_in[1];   // [2,E]: row0=src, row1=dst
    const int*   pairs = (const int*)d_in[3];   // [P,2]
    const float* W1    = (const float*)d_in[4];
    const float* b1    = (const float*)d_in[5];
    const float* W2    = (const float*)d_in[6];
    const float* b2    = (const float*)d_in[7];
    const float* Wh    = (const float*)d_in[8];
    const float* bh    = (const float*)d_in[9];

    const int N = in_sizes[0] / 128;
    const int E = in_sizes[1] / 2;
    const int P = in_sizes[3] / 2;
    const int* srcArr = ei;
    const int* dstArr = ei + E;

    const size_t feat_total = (size_t)N * 64;
    const int NB = (N + BNODES - 1) / BNODES;      // dst buckets
    const int tileBlocks = (E + TILE - 1) / TILE;  // edge tiles
    const int gemm_blocks = (N + 63) / 64;
    const int pull_blocks = (N + 7) / 8;

    auto align512 = [](size_t v) { return (v + 511) & ~(size_t)511; };

    char* ws = (char*)d_ws;
    size_t off = 0;
    float*  dis    = (float*) (ws + off); off += align512((size_t)N * 4);
    int*    rowptr = (int*)   (ws + off); off += align512(((size_t)N + 1) * 4);
    int*    subcnt = (int*)   (ws + off); off += align512((size_t)NB * 4);
    int*    subcur = (int*)   (ws + off); off += align512((size_t)NB * 4);
    int*    subptr = (int*)   (ws + off); off += align512(((size_t)NB + 1) * 4);
    float2* s01    = (float2*)(ws + off); off += align512((size_t)N * 8);
    int*    srcs   = (int*)   (ws + off); off += align512((size_t)E * 4);
    // bufA slot holds: ebuf (E ints) early, then bf16 hpre [N][64]; sized for max.
    size_t bufA_bytes = align512((size_t)E * 4 > feat_total * 2 ? (size_t)E * 4
                                                                : feat_total * 2);
    unsigned short* bufA = (unsigned short*)(ws + off); off += bufA_bytes;
    float*  bufB   = (float*) (ws + off); off += align512(feat_total * 4);
    int*    ebuf   = (int*)bufA;  // aliased: consumed by bin_fill before gemm1 writes bufA
    const bool csr_ok = (off <= ws_size) && (NB <= 1024) && (N <= (1 << PACK_SHIFT));

    if (csr_ok) {
        // ---- CSR build ----
        zero2_kernel<<<1, 1024, 0, stream>>>(subcnt, subcur, NB);
        count_buckets<<<tileBlocks, 256, 0, stream>>>(dstArr, subcnt, NB, E);
        scan_small_kernel<<<1, 1024, 0, stream>>>(subcnt, subptr, NB, E);
        block_scatter<<<tileBlocks, 256, 0, stream>>>(srcArr, dstArr, subptr, subcur,
                                                      ebuf, NB, E);
        bin_fill_kernel<<<NB, 256, 0, stream>>>(ebuf, subptr, rowptr, dis, srcs, NB, N, E);

        // ---- layer 1: hpre(bf16) = (x@W1)*dis ; bufB(fp32) = relu(...) ----
        gemm_tiled<128, true, unsigned short><<<gemm_blocks, THREADS, 0, stream>>>(
            x, W1, dis, bufA, N);
        pull2_kernel<false><<<pull_blocks, THREADS, 0, stream>>>(
            (const unsigned*)bufA, rowptr, srcs, dis, b1, nullptr, bufB, nullptr, N);

        // ---- layer 2 + head dots fused ----
        gemm_tiled<64, true, unsigned short><<<gemm_blocks, THREADS, 0, stream>>>(
            bufB, W2, dis, bufA, N);
        pull2_kernel<true><<<pull_blocks, THREADS, 0, stream>>>(
            (const unsigned*)bufA, rowptr, srcs, dis, b2, Wh, nullptr, s01, N);

        // ---- pair gather ----
        pair_kernel<<<(P + THREADS - 1) / THREADS, THREADS, 0, stream>>>(
            s01, pairs, bh, (float*)d_out, P);
    } else {
        // ---- fallback: atomic push path, fp32 ----
        size_t o2 = 0;
        float* deg  = (float*)(ws + o2); o2 += align512((size_t)N * 4);
        float* bA   = (float*)(ws + o2); o2 += align512(feat_total * 4);
        float* bB   = (float*)(ws + o2);
        const size_t edge_threads = (size_t)(E + N) * 64;
        const int eblocks = (E + THREADS - 1) / THREADS;

        hipMemsetAsync(deg, 0, (size_t)N * 4, stream);
        degf_kernel<<<eblocks, THREADS, 0, stream>>>(dstArr, deg, E);
        rsqrtf_kernel<<<(N + THREADS - 1) / THREADS, THREADS, 0, stream>>>(deg, N);

        gemm_tiled<128, false, float><<<gemm_blocks, THREADS, 0, stream>>>(x, W1, deg, bA, N);
        hipMemsetAsync(bB, 0, feat_total * 4, stream);
        scatter_kernel<<<(unsigned)((edge_threads + THREADS - 1) / THREADS), THREADS, 0, stream>>>(
            bA, srcArr, dstArr, deg, bB, E, N);
        bias_relu_kernel<<<(unsigned)((feat_total + THREADS - 1) / THREADS), THREADS, 0, stream>>>(
            bB, b1, (long long)feat_total);

        gemm_tiled<64, false, float><<<gemm_blocks, THREADS, 0, stream>>>(bB, W2, deg, bA, N);
        hipMemsetAsync(bB, 0, feat_total * 4, stream);
        scatter_kernel<<<(unsigned)((edge_threads + THREADS - 1) / THREADS), THREADS, 0, stream>>>(
            bA, srcArr, dstArr, deg, bB, E, N);
        bias_relu_kernel<<<(unsigned)((feat_total + THREADS - 1) / THREADS), THREADS, 0, stream>>>(
            bB, b2, (long long)feat_total);

        head_kernel<<<(unsigned)(((size_t)P * 64 + THREADS - 1) / THREADS), THREADS, 0, stream>>>(
            bB, pairs, Wh, bh, (float*)d_out, P);
    }
}

// Round 12
// 177.305 us; speedup vs baseline: 1.2458x; 1.1300x over previous
//
#include <hip/hip_runtime.h>

#define THREADS 256
#define BNODES 256           // nodes per dst-bucket
#define PACK_SHIFT 20        // src in low 20 bits, local dst in bits 20..27
#define TILE 2048            // edges per block in scatter

__device__ __forceinline__ unsigned short f2bf(float f) {
    unsigned u = __float_as_uint(f);
    unsigned r = (u + 0x7fff + ((u >> 16) & 1)) >> 16;  // RNE
    return (unsigned short)r;
}
__device__ __forceinline__ float bf2f_lo(unsigned v) { return __uint_as_float(v << 16); }
__device__ __forceinline__ float bf2f_hi(unsigned v) { return __uint_as_float(v & 0xffff0000u); }

// ---------------- CSR build: fixed-capacity bucket scatter (single pass over edges) ----

__global__ void zero1_kernel(int* __restrict__ a, int n) {
    for (int i = threadIdx.x; i < n; i += 1024) a[i] = 0;
}

// exclusive scan of cnt[0..nb) -> ptr; ptr[nb] = total. nb <= 1024.
__global__ void scan_small_kernel(const int* __restrict__ cnt, int* __restrict__ ptr,
                                  int nb, int total) {
    __shared__ int sh[1024];
    int t = threadIdx.x;
    int v = (t < nb) ? cnt[t] : 0;
    sh[t] = v;
    __syncthreads();
    for (int off = 1; off < 1024; off <<= 1) {
        int add = (t >= off) ? sh[t - off] : 0;
        __syncthreads();
        sh[t] += add;
        __syncthreads();
    }
    if (t < nb) ptr[t] = sh[t] - v;
    if (t == 0) ptr[nb] = total;
}

// One pass: per-block LDS histogram, claim per-(block,bucket) base from bucketCur,
// place packed words into bucket b's fixed region [b*CAP, (b+1)*CAP).
__global__ __launch_bounds__(512) void block_scatter(const int* __restrict__ src,
                                                     const int* __restrict__ dst,
                                                     int* __restrict__ bucketCur,
                                                     int* __restrict__ ebuf,
                                                     int NB, int CAP, int E) {
    __shared__ int h[1024];
    __shared__ int bb[1024];
    int t = threadIdx.x;
    for (int i = t; i < NB; i += 512) h[i] = 0;
    __syncthreads();
    int e0 = blockIdx.x * TILE;
    int n = min(TILE, E - e0);
    int d[4]; bool has[4];
    #pragma unroll
    for (int k = 0; k < 4; ++k) {
        int j = t + k * 512;
        has[k] = j < n;
        d[k] = has[k] ? dst[e0 + j] : 0;
    }
    #pragma unroll
    for (int k = 0; k < 4; ++k)
        if (has[k]) atomicAdd(&h[d[k] >> 8], 1);
    __syncthreads();
    for (int i = t; i < NB; i += 512) {
        int c = h[i];
        bb[i] = (c > 0) ? (i * CAP + atomicAdd(&bucketCur[i], c)) : 0;
        h[i] = 0;  // reuse as cursor
    }
    __syncthreads();
    int s[4];
    #pragma unroll
    for (int k = 0; k < 4; ++k) {
        int j = t + k * 512;
        s[k] = has[k] ? src[e0 + j] : 0;
    }
    #pragma unroll
    for (int k = 0; k < 4; ++k)
        if (has[k]) {
            int b = d[k] >> 8;
            int pos = bb[b] + atomicAdd(&h[b], 1);
            ebuf[pos] = s[k] | ((d[k] & (BNODES - 1)) << PACK_SHIFT);
        }
}

// One block per bucket: node degrees (LDS) -> dis + rowptr (dense), then order
// the bucket's region into srcs at the global CSR offset.
__global__ __launch_bounds__(256) void bin_fill_kernel(const int* __restrict__ ebuf,
                                                       const int* __restrict__ subptr,
                                                       int* __restrict__ rowptr,
                                                       float* __restrict__ dis,
                                                       int* __restrict__ srcs,
                                                       int NB, int CAP, int N, int E) {
    __shared__ int cntL[BNODES];
    __shared__ int rb[BNODES];
    int b = blockIdx.x;
    int t = threadIdx.x;
    int base = b * BNODES;
    int g0 = subptr[b];
    int cnt = subptr[b + 1] - g0;
    int s0 = b * CAP, s1 = s0 + cnt;
    cntL[t] = 0;
    __syncthreads();
    for (int i = s0 + t; i < s1; i += 256)
        atomicAdd(&cntL[((unsigned)ebuf[i]) >> PACK_SHIFT], 1);
    __syncthreads();
    int myc = cntL[t];
    if (base + t < N) dis[base + t] = rsqrtf((float)myc + 1.0f);
    rb[t] = myc;
    __syncthreads();
    #pragma unroll
    for (int off = 1; off < 256; off <<= 1) {
        int add = (t >= off) ? rb[t - off] : 0;
        __syncthreads();
        rb[t] += add;
        __syncthreads();
    }
    int excl = rb[t] - myc;
    rb[t] = g0 + excl;
    if (base + t < N) rowptr[base + t] = g0 + excl;
    if (b == NB - 1 && t == 0) rowptr[N] = E;
    cntL[t] = 0;  // reuse as cursor
    __syncthreads();
    const int mask = (1 << PACK_SHIFT) - 1;
    for (int i = s0 + t; i < s1; i += 256) {
        int w = ebuf[i];
        int local = ((unsigned)w) >> PACK_SHIFT;
        int pos = rb[local] + atomicAdd(&cntL[local], 1);
        srcs[pos] = w & mask;
    }
}

// ---------------- tiled GEMM ----------------
template<int K, bool SCALE, typename YT>
__global__ __launch_bounds__(256, 4) void gemm_tiled(const float* __restrict__ X,
                                                     const float* __restrict__ W,
                                                     const float* __restrict__ dis,
                                                     YT* __restrict__ Y, int M) {
    __shared__ float Ws[32 * 64];   // current K-chunk of W
    __shared__ float Xs[32 * 68];   // transposed X chunk [k][row], pitch 68
    const int t = threadIdx.x;

    const int r0 = blockIdx.x * 64;
    const int wave = t >> 6;
    const int lane = t & 63;
    const int tr = lane & 15;
    const int tc = (lane >> 4) + wave * 4;

    float acc[4][4] = {};

    #pragma unroll 1
    for (int kc = 0; kc < K; kc += 32) {
        __syncthreads();
        #pragma unroll
        for (int it = 0; it < 2; ++it) {
            int i = it * 256 + t;
            ((float4*)Ws)[i] = ((const float4*)(W + (size_t)kc * 64))[i];
        }
        #pragma unroll
        for (int it = 0; it < 2; ++it) {
            int i = it * 256 + t;
            int row = i & 63;
            int kq = i >> 6;           // 0..7
            int gr = r0 + row;
            if (gr >= M) gr = M - 1;
            float4 v = *(const float4*)(X + (size_t)gr * K + kc + kq * 4);
            Xs[(kq * 4 + 0) * 68 + row] = v.x;
            Xs[(kq * 4 + 1) * 68 + row] = v.y;
            Xs[(kq * 4 + 2) * 68 + row] = v.z;
            Xs[(kq * 4 + 3) * 68 + row] = v.w;
        }
        __syncthreads();
        #pragma unroll
        for (int kk = 0; kk < 32; ++kk) {
            float4 xv = *(const float4*)(Xs + kk * 68 + tr * 4);
            float4 wv = *(const float4*)(Ws + kk * 64 + tc * 4);
            acc[0][0] = fmaf(xv.x, wv.x, acc[0][0]);
            acc[0][1] = fmaf(xv.x, wv.y, acc[0][1]);
            acc[0][2] = fmaf(xv.x, wv.z, acc[0][2]);
            acc[0][3] = fmaf(xv.x, wv.w, acc[0][3]);
            acc[1][0] = fmaf(xv.y, wv.x, acc[1][0]);
            acc[1][1] = fmaf(xv.y, wv.y, acc[1][1]);
            acc[1][2] = fmaf(xv.y, wv.z, acc[1][2]);
            acc[1][3] = fmaf(xv.y, wv.w, acc[1][3]);
            acc[2][0] = fmaf(xv.z, wv.x, acc[2][0]);
            acc[2][1] = fmaf(xv.z, wv.y, acc[2][1]);
            acc[2][2] = fmaf(xv.z, wv.z, acc[2][2]);
            acc[2][3] = fmaf(xv.z, wv.w, acc[2][3]);
            acc[3][0] = fmaf(xv.w, wv.x, acc[3][0]);
            acc[3][1] = fmaf(xv.w, wv.y, acc[3][1]);
            acc[3][2] = fmaf(xv.w, wv.z, acc[3][2]);
            acc[3][3] = fmaf(xv.w, wv.w, acc[3][3]);
        }
    }

    #pragma unroll
    for (int i = 0; i < 4; ++i) {
        int row = r0 + tr * 4 + i;
        if (row < M) {
            float s = SCALE ? dis[row] : 1.0f;
            if constexpr (sizeof(YT) == 2) {
                ushort4 st;
                st.x = f2bf(acc[i][0] * s);
                st.y = f2bf(acc[i][1] * s);
                st.z = f2bf(acc[i][2] * s);
                st.w = f2bf(acc[i][3] * s);
                *(ushort4*)((unsigned short*)Y + (size_t)row * 64 + tc * 4) = st;
            } else {
                float4 st = make_float4(acc[i][0] * s, acc[i][1] * s,
                                        acc[i][2] * s, acc[i][3] * s);
                *(float4*)((float*)Y + (size_t)row * 64 + tc * 4) = st;
            }
        }
    }
}

// ---------------- pull aggregate ----------------
// 2 nodes/wave; per node: 16 lanes x uint2 (4 bf16 feats) x 2 edge-slots.
// Lock-step masked loop (uniform trip via __any); eo partials combined pre-ReLU.
template<bool HEAD>
__global__ __launch_bounds__(256) void pull2_kernel(const unsigned* __restrict__ hpre2,
                                                    const int* __restrict__ rowptr,
                                                    const int* __restrict__ srcs,
                                                    const float* __restrict__ dis,
                                                    const float* __restrict__ b,
                                                    const float* __restrict__ Wh,
                                                    float* __restrict__ out,
                                                    float2* __restrict__ s01, int N) {
    int tid = threadIdx.x;
    int lane = tid & 63;
    int half = lane >> 5;          // which node of the wave's pair
    int sub = lane & 31;
    int eo = sub >> 4;             // edge slot 0/1
    int l = sub & 15;              // feature quad: uints 2l,2l+1 = feats 4l..4l+3
    int node = blockIdx.x * 8 + (tid >> 6) * 2 + half;
    bool valid = node < N;
    int nc = valid ? node : N - 1;
    int i0 = rowptr[nc];
    int end = valid ? rowptr[nc + 1] : i0;

    // self loop counted once (eo==0 lanes)
    uint2 sv = *(const uint2*)(hpre2 + (size_t)nc * 32 + 2 * l);
    float a0 = eo ? 0.f : bf2f_lo(sv.x);
    float a1 = eo ? 0.f : bf2f_hi(sv.x);
    float a2 = eo ? 0.f : bf2f_lo(sv.y);
    float a3 = eo ? 0.f : bf2f_hi(sv.y);

    int i = i0 + eo;
    while (__any(i < end)) {
        #pragma unroll
        for (int k = 0; k < 4; ++k) {        // 4 steps x 2 slots = 8 edges/node/iter
            int idx = i + 2 * k;
            bool m = idx < end;
            int s = srcs[m ? idx : 0];       // clamp to edge 0 (row cache-hot)
            uint2 v = *(const uint2*)(hpre2 + (size_t)s * 32 + 2 * l);
            a0 += m ? bf2f_lo(v.x) : 0.f;
            a1 += m ? bf2f_hi(v.x) : 0.f;
            a2 += m ? bf2f_lo(v.y) : 0.f;
            a3 += m ? bf2f_hi(v.y) : 0.f;
        }
        i += 8;
    }

    // combine the two edge-slot partials (lanes eo==0 get totals)
    a0 += __shfl_down(a0, 16, 32);
    a1 += __shfl_down(a1, 16, 32);
    a2 += __shfl_down(a2, 16, 32);
    a3 += __shfl_down(a3, 16, 32);

    float d = dis[nc];
    float4 bb = ((const float4*)b)[l];
    float o0 = fmaf(a0, d, bb.x);
    float o1 = fmaf(a1, d, bb.y);
    float o2 = fmaf(a2, d, bb.z);
    float o3 = fmaf(a3, d, bb.w);
    o0 = o0 > 0.f ? o0 : 0.f;
    o1 = o1 > 0.f ? o1 : 0.f;
    o2 = o2 > 0.f ? o2 : 0.f;
    o3 = o3 > 0.f ? o3 : 0.f;

    if (HEAD) {
        float4 w0 = ((const float4*)Wh)[l];
        float4 w1 = ((const float4*)(Wh + 64))[l];
        float p0 = o0 * w0.x + o1 * w0.y + o2 * w0.z + o3 * w0.w;
        float p1 = o0 * w1.x + o1 * w1.y + o2 * w1.z + o3 * w1.w;
        #pragma unroll
        for (int off = 8; off > 0; off >>= 1) {
            p0 += __shfl_down(p0, off, 16);
            p1 += __shfl_down(p1, off, 16);
        }
        if (valid && sub == 0) s01[node] = make_float2(p0, p1);
    } else {
        if (valid && eo == 0)
            *(float4*)(out + (size_t)node * 64 + 4 * l) = make_float4(o0, o1, o2, o3);
    }
}

// out[p] = s01[p0].x + s01[p1].y + bh  (s01 is ~800KB -> L2-resident gathers)
__global__ void pair_kernel(const float2* __restrict__ s01, const int* __restrict__ pairs,
                            const float* __restrict__ bh, float* __restrict__ out, int P) {
    int p = blockIdx.x * blockDim.x + threadIdx.x;
    if (p < P) {
        int p0 = pairs[2 * (size_t)p];
        int p1 = pairs[2 * (size_t)p + 1];
        out[p] = s01[p0].x + s01[p1].y + bh[0];
    }
}

// ---------------- fallback (atomic push, full fp32) ----------------
__global__ void degf_kernel(const int* __restrict__ dst, float* __restrict__ deg, int E) {
    int e = blockIdx.x * blockDim.x + threadIdx.x;
    if (e < E) atomicAdd(&deg[dst[e]], 1.0f);
}
__global__ void rsqrtf_kernel(float* deg, int N) {
    int i = blockIdx.x * blockDim.x + threadIdx.x;
    if (i < N) deg[i] = rsqrtf(deg[i] + 1.0f);
}
__global__ void scatter_kernel(const float* __restrict__ h, const int* __restrict__ src,
                               const int* __restrict__ dst, const float* __restrict__ dis,
                               float* __restrict__ agg, int E, int N) {
    long long idx = (long long)blockIdx.x * blockDim.x + threadIdx.x;
    int e = (int)(idx >> 6);
    int f = (int)(idx & 63);
    if (e >= E + N) return;
    int s, d;
    if (e < E) { s = src[e]; d = dst[e]; } else { s = e - E; d = s; }
    float norm = dis[s] * dis[d];
    atomicAdd(&agg[(size_t)d * 64 + f], h[(size_t)s * 64 + f] * norm);
}
__global__ void bias_relu_kernel(float* __restrict__ buf, const float* __restrict__ b,
                                 long long total) {
    long long i = (long long)blockIdx.x * blockDim.x + threadIdx.x;
    if (i < total) {
        float v = buf[i] + b[(int)(i & 63)];
        buf[i] = v > 0.f ? v : 0.f;
    }
}
__global__ void head_kernel(const float* __restrict__ h, const int* __restrict__ pairs,
                            const float* __restrict__ Wh, const float* __restrict__ bh,
                            float* __restrict__ out, int P) {
    long long idx = (long long)blockIdx.x * blockDim.x + threadIdx.x;
    int p = (int)(idx >> 6);
    int lane = threadIdx.x & 63;
    if (p >= P) return;
    int p0 = pairs[2 * (size_t)p];
    int p1 = pairs[2 * (size_t)p + 1];
    float v = h[(size_t)p0 * 64 + lane] * Wh[lane]
            + h[(size_t)p1 * 64 + lane] * Wh[64 + lane];
    #pragma unroll
    for (int off = 32; off > 0; off >>= 1) v += __shfl_down(v, off);
    if (lane == 0) out[p] = v + bh[0];
}

extern "C" void kernel_launch(void* const* d_in, const int* in_sizes, int n_in,
                              void* d_out, int out_size, void* d_ws, size_t ws_size,
                              hipStream_t stream) {
    const float* x     = (const float*)d_in[0];
    const int*   ei    = (const int*)d_in[1];   // [2,E]: row0=src, row1=dst
    const int*   pairs = (const int*)d_in[3];   // [P,2]
    const float* W1    = (const float*)d_in[4];
    const float* b1    = (const float*)d_in[5];
    const float* W2    = (const float*)d_in[6];
    const float* b2    = (const float*)d_in[7];
    const float* Wh    = (const float*)d_in[8];
    const float* bh    = (const float*)d_in[9];

    const int N = in_sizes[0] / 128;
    const int E = in_sizes[1] / 2;
    const int P = in_sizes[3] / 2;
    const int* srcArr = ei;
    const int* dstArr = ei + E;

    const size_t feat_total = (size_t)N * 64;
    const int NB = (N + BNODES - 1) / BNODES;      // dst buckets
    const int tileBlocks = (E + TILE - 1) / TILE;  // edge tiles
    const int gemm_blocks = (N + 63) / 64;
    const int pull_blocks = (N + 7) / 8;

    auto align512 = [](size_t v) { return (v + 511) & ~(size_t)511; };

    char* ws = (char*)d_ws;
    size_t off = 0;
    float*  dis    = (float*) (ws + off); off += align512((size_t)N * 4);
    int*    rowptr = (int*)   (ws + off); off += align512(((size_t)N + 1) * 4);
    int*    bucketCur = (int*)(ws + off); off += align512((size_t)NB * 4);
    int*    subptr = (int*)   (ws + off); off += align512(((size_t)NB + 1) * 4);
    float2* s01    = (float2*)(ws + off); off += align512((size_t)N * 8);
    int*    srcs   = (int*)   (ws + off); off += align512((size_t)E * 4);
    // bufA slot holds: ebuf (bucket regions) early, then bf16 hpre [N][64].
    size_t bufA_bytes = align512((size_t)E * 4 > feat_total * 2 ? (size_t)E * 4
                                                                : feat_total * 2);
    unsigned short* bufA = (unsigned short*)(ws + off); off += bufA_bytes;
    float*  bufB   = (float*) (ws + off); off += align512(feat_total * 4);
    int*    ebuf   = (int*)bufA;  // aliased: consumed by bin_fill before gemm1 writes bufA

    const int CAP = (int)(bufA_bytes / ((size_t)4 * NB));       // slots per bucket
    const int avgB = (E + NB - 1) / NB;                         // expected bucket fill
    const bool csr_ok = (off <= ws_size) && (NB <= 1024) && (N <= (1 << PACK_SHIFT)) &&
                        (CAP >= avgB + (avgB >> 2) + 1024);     // >25%+1024 slack

    if (csr_ok) {
        // ---- CSR build (single edge pass) ----
        zero1_kernel<<<1, 1024, 0, stream>>>(bucketCur, NB);
        block_scatter<<<tileBlocks, 512, 0, stream>>>(srcArr, dstArr, bucketCur,
                                                      ebuf, NB, CAP, E);
        scan_small_kernel<<<1, 1024, 0, stream>>>(bucketCur, subptr, NB, E);
        bin_fill_kernel<<<NB, 256, 0, stream>>>(ebuf, subptr, rowptr, dis, srcs,
                                                NB, CAP, N, E);

        // ---- layer 1: hpre(bf16) = (x@W1)*dis ; bufB(fp32) = relu(...) ----
        gemm_tiled<128, true, unsigned short><<<gemm_blocks, THREADS, 0, stream>>>(
            x, W1, dis, bufA, N);
        pull2_kernel<false><<<pull_blocks, THREADS, 0, stream>>>(
            (const unsigned*)bufA, rowptr, srcs, dis, b1, nullptr, bufB, nullptr, N);

        // ---- layer 2 + head dots fused ----
        gemm_tiled<64, true, unsigned short><<<gemm_blocks, THREADS, 0, stream>>>(
            bufB, W2, dis, bufA, N);
        pull2_kernel<true><<<pull_blocks, THREADS, 0, stream>>>(
            (const unsigned*)bufA, rowptr, srcs, dis, b2, Wh, nullptr, s01, N);

        // ---- pair gather ----
        pair_kernel<<<(P + THREADS - 1) / THREADS, THREADS, 0, stream>>>(
            s01, pairs, bh, (float*)d_out, P);
    } else {
        // ---- fallback: atomic push path, fp32 ----
        size_t o2 = 0;
        float* deg  = (float*)(ws + o2); o2 += align512((size_t)N * 4);
        float* bA   = (float*)(ws + o2); o2 += align512(feat_total * 4);
        float* bB   = (float*)(ws + o2);
        const size_t edge_threads = (size_t)(E + N) * 64;
        const int eblocks = (E + THREADS - 1) / THREADS;

        hipMemsetAsync(deg, 0, (size_t)N * 4, stream);
        degf_kernel<<<eblocks, THREADS, 0, stream>>>(dstArr, deg, E);
        rsqrtf_kernel<<<(N + THREADS - 1) / THREADS, THREADS, 0, stream>>>(deg, N);

        gemm_tiled<128, false, float><<<gemm_blocks, THREADS, 0, stream>>>(x, W1, deg, bA, N);
        hipMemsetAsync(bB, 0, feat_total * 4, stream);
        scatter_kernel<<<(unsigned)((edge_threads + THREADS - 1) / THREADS), THREADS, 0, stream>>>(
            bA, srcArr, dstArr, deg, bB, E, N);
        bias_relu_kernel<<<(unsigned)((feat_total + THREADS - 1) / THREADS), THREADS, 0, stream>>>(
            bB, b1, (long long)feat_total);

        gemm_tiled<64, false, float><<<gemm_blocks, THREADS, 0, stream>>>(bB, W2, deg, bA, N);
        hipMemsetAsync(bB, 0, feat_total * 4, stream);
        scatter_kernel<<<(unsigned)((edge_threads + THREADS - 1) / THREADS), THREADS, 0, stream>>>(
            bA, srcArr, dstArr, deg, bB, E, N);
        bias_relu_kernel<<<(unsigned)((feat_total + THREADS - 1) / THREADS), THREADS, 0, stream>>>(
            bB, b2, (long long)feat_total);

        head_kernel<<<(unsigned)(((size_t)P * 64 + THREADS - 1) / THREADS), THREADS, 0, stream>>>(
            bB, pairs, Wh, bh, (float*)d_out, P);
    }
}

// Round 13
// 161.861 us; speedup vs baseline: 1.3647x; 1.0954x over previous
//
#include <hip/hip_runtime.h>

#define THREADS 256
#define BNODES 256           // nodes per dst-bucket
#define PACK_SHIFT 20        // src in low 20 bits, local dst in bits 20..27
#define TILE 4096            // edges per block in scatter

__device__ __forceinline__ unsigned short f2bf(float f) {
    unsigned u = __float_as_uint(f);
    unsigned r = (u + 0x7fff + ((u >> 16) & 1)) >> 16;  // RNE
    return (unsigned short)r;
}
__device__ __forceinline__ float bf2f_lo(unsigned v) { return __uint_as_float(v << 16); }
__device__ __forceinline__ float bf2f_hi(unsigned v) { return __uint_as_float(v & 0xffff0000u); }

// ---------------- CSR build: fixed-capacity bucket scatter, region-space CSR ----------

__global__ void zero1_kernel(int* __restrict__ a, int n) {
    for (int i = threadIdx.x; i < n; i += 1024) a[i] = 0;
}

// Single pass: per-block LDS histogram, claim per-(block,bucket) base from bucketCur,
// place packed words into bucket b's fixed region [b*CAP, (b+1)*CAP).
__global__ __launch_bounds__(512) void block_scatter(const int* __restrict__ src,
                                                     const int* __restrict__ dst,
                                                     int* __restrict__ bucketCur,
                                                     int* __restrict__ ebuf,
                                                     int NB, int CAP, int E) {
    __shared__ int h[1024];
    __shared__ int bb[1024];
    int t = threadIdx.x;
    for (int i = t; i < NB; i += 512) h[i] = 0;
    __syncthreads();
    int e0 = blockIdx.x * TILE;
    int n = min(TILE, E - e0);
    int d[8]; bool has[8];
    #pragma unroll
    for (int k = 0; k < 8; ++k) {
        int j = t + k * 512;
        has[k] = j < n;
        d[k] = has[k] ? dst[e0 + j] : 0;
    }
    #pragma unroll
    for (int k = 0; k < 8; ++k)
        if (has[k]) atomicAdd(&h[d[k] >> 8], 1);
    __syncthreads();
    for (int i = t; i < NB; i += 512) {
        int c = h[i];
        bb[i] = (c > 0) ? (i * CAP + atomicAdd(&bucketCur[i], c)) : 0;
        h[i] = 0;  // reuse as cursor
    }
    __syncthreads();
    int s[8];
    #pragma unroll
    for (int k = 0; k < 8; ++k) {
        int j = t + k * 512;
        s[k] = has[k] ? src[e0 + j] : 0;
    }
    #pragma unroll
    for (int k = 0; k < 8; ++k)
        if (has[k]) {
            int b = d[k] >> 8;
            int pos = bb[b] + atomicAdd(&h[b], 1);
            ebuf[pos] = s[k] | ((d[k] & (BNODES - 1)) << PACK_SHIFT);
        }
}

// One block per bucket: node degrees (LDS) -> dis + rowptr2{start,end} (region space),
// then order the bucket's region into srcs (also region space).
__global__ __launch_bounds__(512) void bin_fill_kernel(const int* __restrict__ ebuf,
                                                       const int* __restrict__ bucketCnt,
                                                       int2* __restrict__ rowptr2,
                                                       float* __restrict__ dis,
                                                       int* __restrict__ srcs,
                                                       int CAP, int N) {
    __shared__ int cntL[BNODES];
    __shared__ int rb[BNODES];
    int b = blockIdx.x;
    int t = threadIdx.x;
    int base = b * BNODES;
    int cnt = bucketCnt[b];
    int s0 = b * CAP, s1 = s0 + cnt;
    if (t < BNODES) cntL[t] = 0;
    __syncthreads();
    for (int i = s0 + t; i < s1; i += 512)
        atomicAdd(&cntL[((unsigned)ebuf[i]) >> PACK_SHIFT], 1);
    __syncthreads();
    int myc = 0;
    if (t < BNODES) {
        myc = cntL[t];
        if (base + t < N) dis[base + t] = rsqrtf((float)myc + 1.0f);
        rb[t] = myc;
    }
    __syncthreads();
    #pragma unroll
    for (int off = 1; off < BNODES; off <<= 1) {
        int add = (t < BNODES && t >= off) ? rb[t - off] : 0;
        __syncthreads();
        if (t < BNODES) rb[t] += add;
        __syncthreads();
    }
    if (t < BNODES) {
        int start = s0 + rb[t] - myc;
        if (base + t < N) rowptr2[base + t] = make_int2(start, start + myc);
        rb[t] = start;
        cntL[t] = 0;  // reuse as cursor
    }
    __syncthreads();
    const int mask = (1 << PACK_SHIFT) - 1;
    for (int i = s0 + t; i < s1; i += 512) {
        int w = ebuf[i];
        int local = ((unsigned)w) >> PACK_SHIFT;
        int pos = rb[local] + atomicAdd(&cntL[local], 1);
        srcs[pos] = w & mask;
    }
}

// ---------------- tiled GEMM ----------------
template<int K, bool SCALE, typename YT>
__global__ __launch_bounds__(256, 4) void gemm_tiled(const float* __restrict__ X,
                                                     const float* __restrict__ W,
                                                     const float* __restrict__ dis,
                                                     YT* __restrict__ Y, int M) {
    __shared__ float Ws[32 * 64];   // current K-chunk of W
    __shared__ float Xs[32 * 68];   // transposed X chunk [k][row], pitch 68
    const int t = threadIdx.x;

    const int r0 = blockIdx.x * 64;
    const int wave = t >> 6;
    const int lane = t & 63;
    const int tr = lane & 15;
    const int tc = (lane >> 4) + wave * 4;

    float acc[4][4] = {};

    #pragma unroll 1
    for (int kc = 0; kc < K; kc += 32) {
        __syncthreads();
        #pragma unroll
        for (int it = 0; it < 2; ++it) {
            int i = it * 256 + t;
            ((float4*)Ws)[i] = ((const float4*)(W + (size_t)kc * 64))[i];
        }
        #pragma unroll
        for (int it = 0; it < 2; ++it) {
            int i = it * 256 + t;
            int row = i & 63;
            int kq = i >> 6;           // 0..7
            int gr = r0 + row;
            if (gr >= M) gr = M - 1;
            float4 v = *(const float4*)(X + (size_t)gr * K + kc + kq * 4);
            Xs[(kq * 4 + 0) * 68 + row] = v.x;
            Xs[(kq * 4 + 1) * 68 + row] = v.y;
            Xs[(kq * 4 + 2) * 68 + row] = v.z;
            Xs[(kq * 4 + 3) * 68 + row] = v.w;
        }
        __syncthreads();
        #pragma unroll
        for (int kk = 0; kk < 32; ++kk) {
            float4 xv = *(const float4*)(Xs + kk * 68 + tr * 4);
            float4 wv = *(const float4*)(Ws + kk * 64 + tc * 4);
            acc[0][0] = fmaf(xv.x, wv.x, acc[0][0]);
            acc[0][1] = fmaf(xv.x, wv.y, acc[0][1]);
            acc[0][2] = fmaf(xv.x, wv.z, acc[0][2]);
            acc[0][3] = fmaf(xv.x, wv.w, acc[0][3]);
            acc[1][0] = fmaf(xv.y, wv.x, acc[1][0]);
            acc[1][1] = fmaf(xv.y, wv.y, acc[1][1]);
            acc[1][2] = fmaf(xv.y, wv.z, acc[1][2]);
            acc[1][3] = fmaf(xv.y, wv.w, acc[1][3]);
            acc[2][0] = fmaf(xv.z, wv.x, acc[2][0]);
            acc[2][1] = fmaf(xv.z, wv.y, acc[2][1]);
            acc[2][2] = fmaf(xv.z, wv.z, acc[2][2]);
            acc[2][3] = fmaf(xv.z, wv.w, acc[2][3]);
            acc[3][0] = fmaf(xv.w, wv.x, acc[3][0]);
            acc[3][1] = fmaf(xv.w, wv.y, acc[3][1]);
            acc[3][2] = fmaf(xv.w, wv.z, acc[3][2]);
            acc[3][3] = fmaf(xv.w, wv.w, acc[3][3]);
        }
    }

    #pragma unroll
    for (int i = 0; i < 4; ++i) {
        int row = r0 + tr * 4 + i;
        if (row < M) {
            float s = SCALE ? dis[row] : 1.0f;
            if constexpr (sizeof(YT) == 2) {
                ushort4 st;
                st.x = f2bf(acc[i][0] * s);
                st.y = f2bf(acc[i][1] * s);
                st.z = f2bf(acc[i][2] * s);
                st.w = f2bf(acc[i][3] * s);
                *(ushort4*)((unsigned short*)Y + (size_t)row * 64 + tc * 4) = st;
            } else {
                float4 st = make_float4(acc[i][0] * s, acc[i][1] * s,
                                        acc[i][2] * s, acc[i][3] * s);
                *(float4*)((float*)Y + (size_t)row * 64 + tc * 4) = st;
            }
        }
    }
}

// ---------------- pull aggregate ----------------
// 2 nodes/wave; per node: 16 lanes x uint2 (4 bf16 feats) x 2 edge-slots.
// Lock-step masked loop (uniform trip via __any); eo partials combined pre-ReLU.
template<bool HEAD>
__global__ __launch_bounds__(256) void pull2_kernel(const unsigned* __restrict__ hpre2,
                                                    const int2* __restrict__ rowptr2,
                                                    const int* __restrict__ srcs,
                                                    const float* __restrict__ dis,
                                                    const float* __restrict__ b,
                                                    const float* __restrict__ Wh,
                                                    float* __restrict__ out,
                                                    float2* __restrict__ s01, int N) {
    int tid = threadIdx.x;
    int lane = tid & 63;
    int half = lane >> 5;          // which node of the wave's pair
    int sub = lane & 31;
    int eo = sub >> 4;             // edge slot 0/1
    int l = sub & 15;              // feature quad: uints 2l,2l+1 = feats 4l..4l+3
    int node = blockIdx.x * 8 + (tid >> 6) * 2 + half;
    bool valid = node < N;
    int nc = valid ? node : N - 1;
    int2 se = rowptr2[nc];
    int i0 = se.x;
    int end = valid ? se.y : i0;

    // self loop counted once (eo==0 lanes)
    uint2 sv = *(const uint2*)(hpre2 + (size_t)nc * 32 + 2 * l);
    float a0 = eo ? 0.f : bf2f_lo(sv.x);
    float a1 = eo ? 0.f : bf2f_hi(sv.x);
    float a2 = eo ? 0.f : bf2f_lo(sv.y);
    float a3 = eo ? 0.f : bf2f_hi(sv.y);

    int i = i0 + eo;
    while (__any(i < end)) {
        #pragma unroll
        for (int k = 0; k < 4; ++k) {        // 4 steps x 2 slots = 8 edges/node/iter
            int idx = i + 2 * k;
            bool m = idx < end;
            int s = srcs[m ? idx : i0];      // clamp to first edge (row cache-hot)
            uint2 v = *(const uint2*)(hpre2 + (size_t)s * 32 + 2 * l);
            a0 += m ? bf2f_lo(v.x) : 0.f;
            a1 += m ? bf2f_hi(v.x) : 0.f;
            a2 += m ? bf2f_lo(v.y) : 0.f;
            a3 += m ? bf2f_hi(v.y) : 0.f;
        }
        i += 8;
    }

    // combine the two edge-slot partials (lanes eo==0 get totals)
    a0 += __shfl_down(a0, 16, 32);
    a1 += __shfl_down(a1, 16, 32);
    a2 += __shfl_down(a2, 16, 32);
    a3 += __shfl_down(a3, 16, 32);

    float d = dis[nc];
    float4 bb = ((const float4*)b)[l];
    float o0 = fmaf(a0, d, bb.x);
    float o1 = fmaf(a1, d, bb.y);
    float o2 = fmaf(a2, d, bb.z);
    float o3 = fmaf(a3, d, bb.w);
    o0 = o0 > 0.f ? o0 : 0.f;
    o1 = o1 > 0.f ? o1 : 0.f;
    o2 = o2 > 0.f ? o2 : 0.f;
    o3 = o3 > 0.f ? o3 : 0.f;

    if (HEAD) {
        float4 w0 = ((const float4*)Wh)[l];
        float4 w1 = ((const float4*)(Wh + 64))[l];
        float p0 = o0 * w0.x + o1 * w0.y + o2 * w0.z + o3 * w0.w;
        float p1 = o0 * w1.x + o1 * w1.y + o2 * w1.z + o3 * w1.w;
        #pragma unroll
        for (int off = 8; off > 0; off >>= 1) {
            p0 += __shfl_down(p0, off, 16);
            p1 += __shfl_down(p1, off, 16);
        }
        if (valid && sub == 0) s01[node] = make_float2(p0, p1);
    } else {
        if (valid && eo == 0)
            *(float4*)(out + (size_t)node * 64 + 4 * l) = make_float4(o0, o1, o2, o3);
    }
}

// out[p] = s01[p0].x + s01[p1].y + bh  (s01 is ~800KB -> L2-resident gathers)
__global__ void pair_kernel(const float2* __restrict__ s01, const int2* __restrict__ pairs,
                            const float* __restrict__ bh, float* __restrict__ out, int P) {
    int p = blockIdx.x * blockDim.x + threadIdx.x;
    if (p < P) {
        int2 pr = pairs[p];
        out[p] = s01[pr.x].x + s01[pr.y].y + bh[0];
    }
}

// ---------------- fallback (atomic push, full fp32) ----------------
__global__ void degf_kernel(const int* __restrict__ dst, float* __restrict__ deg, int E) {
    int e = blockIdx.x * blockDim.x + threadIdx.x;
    if (e < E) atomicAdd(&deg[dst[e]], 1.0f);
}
__global__ void rsqrtf_kernel(float* deg, int N) {
    int i = blockIdx.x * blockDim.x + threadIdx.x;
    if (i < N) deg[i] = rsqrtf(deg[i] + 1.0f);
}
__global__ void scatter_kernel(const float* __restrict__ h, const int* __restrict__ src,
                               const int* __restrict__ dst, const float* __restrict__ dis,
                               float* __restrict__ agg, int E, int N) {
    long long idx = (long long)blockIdx.x * blockDim.x + threadIdx.x;
    int e = (int)(idx >> 6);
    int f = (int)(idx & 63);
    if (e >= E + N) return;
    int s, d;
    if (e < E) { s = src[e]; d = dst[e]; } else { s = e - E; d = s; }
    float norm = dis[s] * dis[d];
    atomicAdd(&agg[(size_t)d * 64 + f], h[(size_t)s * 64 + f] * norm);
}
__global__ void bias_relu_kernel(float* __restrict__ buf, const float* __restrict__ b,
                                 long long total) {
    long long i = (long long)blockIdx.x * blockDim.x + threadIdx.x;
    if (i < total) {
        float v = buf[i] + b[(int)(i & 63)];
        buf[i] = v > 0.f ? v : 0.f;
    }
}
__global__ void head_kernel(const float* __restrict__ h, const int* __restrict__ pairs,
                            const float* __restrict__ Wh, const float* __restrict__ bh,
                            float* __restrict__ out, int P) {
    long long idx = (long long)blockIdx.x * blockDim.x + threadIdx.x;
    int p = (int)(idx >> 6);
    int lane = threadIdx.x & 63;
    if (p >= P) return;
    int p0 = pairs[2 * (size_t)p];
    int p1 = pairs[2 * (size_t)p + 1];
    float v = h[(size_t)p0 * 64 + lane] * Wh[lane]
            + h[(size_t)p1 * 64 + lane] * Wh[64 + lane];
    #pragma unroll
    for (int off = 32; off > 0; off >>= 1) v += __shfl_down(v, off);
    if (lane == 0) out[p] = v + bh[0];
}

extern "C" void kernel_launch(void* const* d_in, const int* in_sizes, int n_in,
                              void* d_out, int out_size, void* d_ws, size_t ws_size,
                              hipStream_t stream) {
    const float* x     = (const float*)d_in[0];
    const int*   ei    = (const int*)d_in[1];   // [2,E]: row0=src, row1=dst
    const int*   pairs = (const int*)d_in[3];   // [P,2]
    const float* W1    = (const float*)d_in[4];
    const float* b1    = (const float*)d_in[5];
    const float* W2    = (const float*)d_in[6];
    const float* b2    = (const float*)d_in[7];
    const float* Wh    = (const float*)d_in[8];
    const float* bh    = (const float*)d_in[9];

    const int N = in_sizes[0] / 128;
    const int E = in_sizes[1] / 2;
    const int P = in_sizes[3] / 2;
    const int* srcArr = ei;
    const int* dstArr = ei + E;

    const size_t feat_total = (size_t)N * 64;
    const int NB = (N + BNODES - 1) / BNODES;      // dst buckets
    const int tileBlocks = (E + TILE - 1) / TILE;  // edge tiles
    const int gemm_blocks = (N + 63) / 64;
    const int pull_blocks = (N + 7) / 8;

    auto align512 = [](size_t v) { return (v + 511) & ~(size_t)511; };

    char* ws = (char*)d_ws;
    size_t off = 0;
    float*  dis     = (float*) (ws + off); off += align512((size_t)N * 4);
    int2*   rowptr2 = (int2*)  (ws + off); off += align512((size_t)N * 8);
    int*    bucketCur = (int*) (ws + off); off += align512((size_t)NB * 4);
    float2* s01     = (float2*)(ws + off); off += align512((size_t)N * 8);
    // bufA slot: ebuf (bucket regions) early, then bf16 hpre [N][64]
    size_t bufA_bytes = align512((size_t)E * 4 > feat_total * 2 ? (size_t)E * 4
                                                                : feat_total * 2);
    unsigned short* bufA = (unsigned short*)(ws + off); off += bufA_bytes;
    int*    srcs    = (int*)   (ws + off); off += bufA_bytes;   // region-space srcs
    float*  bufB    = (float*) (ws + off); off += align512(feat_total * 4);
    int*    ebuf    = (int*)bufA;  // aliased: consumed by bin_fill before gemm1 writes bufA

    const int CAP = (int)(bufA_bytes / ((size_t)4 * NB));       // slots per bucket
    const int avgB = (E + NB - 1) / NB;                         // expected bucket fill
    const bool csr_ok = (off <= ws_size) && (NB <= 1024) && (N <= (1 << PACK_SHIFT)) &&
                        (CAP >= avgB + (avgB >> 2) + 1024);     // >25%+1024 slack

    if (csr_ok) {
        // ---- CSR build (single edge pass, region-space offsets) ----
        zero1_kernel<<<1, 1024, 0, stream>>>(bucketCur, NB);
        block_scatter<<<tileBlocks, 512, 0, stream>>>(srcArr, dstArr, bucketCur,
                                                      ebuf, NB, CAP, E);
        bin_fill_kernel<<<NB, 512, 0, stream>>>(ebuf, bucketCur, rowptr2, dis, srcs,
                                                CAP, N);

        // ---- layer 1: hpre(bf16) = (x@W1)*dis ; bufB(fp32) = relu(...) ----
        gemm_tiled<128, true, unsigned short><<<gemm_blocks, THREADS, 0, stream>>>(
            x, W1, dis, bufA, N);
        pull2_kernel<false><<<pull_blocks, THREADS, 0, stream>>>(
            (const unsigned*)bufA, rowptr2, srcs, dis, b1, nullptr, bufB, nullptr, N);

        // ---- layer 2 + head dots fused ----
        gemm_tiled<64, true, unsigned short><<<gemm_blocks, THREADS, 0, stream>>>(
            bufB, W2, dis, bufA, N);
        pull2_kernel<true><<<pull_blocks, THREADS, 0, stream>>>(
            (const unsigned*)bufA, rowptr2, srcs, dis, b2, Wh, nullptr, s01, N);

        // ---- pair gather ----
        pair_kernel<<<(P + THREADS - 1) / THREADS, THREADS, 0, stream>>>(
            s01, (const int2*)pairs, bh, (float*)d_out, P);
    } else {
        // ---- fallback: atomic push path, fp32 ----
        size_t o2 = 0;
        float* deg  = (float*)(ws + o2); o2 += align512((size_t)N * 4);
        float* bA   = (float*)(ws + o2); o2 += align512(feat_total * 4);
        float* bB   = (float*)(ws + o2);
        const size_t edge_threads = (size_t)(E + N) * 64;
        const int eblocks = (E + THREADS - 1) / THREADS;

        hipMemsetAsync(deg, 0, (size_t)N * 4, stream);
        degf_kernel<<<eblocks, THREADS, 0, stream>>>(dstArr, deg, E);
        rsqrtf_kernel<<<(N + THREADS - 1) / THREADS, THREADS, 0, stream>>>(deg, N);

        gemm_tiled<128, false, float><<<gemm_blocks, THREADS, 0, stream>>>(x, W1, deg, bA, N);
        hipMemsetAsync(bB, 0, feat_total * 4, stream);
        scatter_kernel<<<(unsigned)((edge_threads + THREADS - 1) / THREADS), THREADS, 0, stream>>>(
            bA, srcArr, dstArr, deg, bB, E, N);
        bias_relu_kernel<<<(unsigned)((feat_total + THREADS - 1) / THREADS), THREADS, 0, stream>>>(
            bB, b1, (long long)feat_total);

        gemm_tiled<64, false, float><<<gemm_blocks, THREADS, 0, stream>>>(bB, W2, deg, bA, N);
        hipMemsetAsync(bB, 0, feat_total * 4, stream);
        scatter_kernel<<<(unsigned)((edge_threads + THREADS - 1) / THREADS), THREADS, 0, stream>>>(
            bA, srcArr, dstArr, deg, bB, E, N);
        bias_relu_kernel<<<(unsigned)((feat_total + THREADS - 1) / THREADS), THREADS, 0, stream>>>(
            bB, b2, (long long)feat_total);

        head_kernel<<<(unsigned)(((size_t)P * 64 + THREADS - 1) / THREADS), THREADS, 0, stream>>>(
            bB, pairs, Wh, bh, (float*)d_out, P);
    }
}

// Round 14
// 159.248 us; speedup vs baseline: 1.3871x; 1.0164x over previous
//
#include <hip/hip_runtime.h>

#define THREADS 256
#define BNODES 256           // nodes per dst-bucket
#define PACK_SHIFT 20        // src in low 20 bits, local dst in bits 20..27
#define TILE 4096            // edges per block in scatter

__device__ __forceinline__ unsigned short f2bf(float f) {
    unsigned u = __float_as_uint(f);
    unsigned r = (u + 0x7fff + ((u >> 16) & 1)) >> 16;  // RNE
    return (unsigned short)r;
}
__device__ __forceinline__ float bf2f_lo(unsigned v) { return __uint_as_float(v << 16); }
__device__ __forceinline__ float bf2f_hi(unsigned v) { return __uint_as_float(v & 0xffff0000u); }

// ---------------- CSR build: fixed-capacity bucket scatter, region-space CSR ----------

__global__ void zero1_kernel(int* __restrict__ a, int n) {
    for (int i = threadIdx.x; i < n; i += 1024) a[i] = 0;
}

__global__ __launch_bounds__(512) void block_scatter(const int* __restrict__ src,
                                                     const int* __restrict__ dst,
                                                     int* __restrict__ bucketCur,
                                                     int* __restrict__ ebuf,
                                                     int NB, int CAP, int E) {
    __shared__ int h[1024];
    __shared__ int bb[1024];
    int t = threadIdx.x;
    for (int i = t; i < NB; i += 512) h[i] = 0;
    __syncthreads();
    int e0 = blockIdx.x * TILE;
    int n = min(TILE, E - e0);
    int d[8]; bool has[8];
    #pragma unroll
    for (int k = 0; k < 8; ++k) {
        int j = t + k * 512;
        has[k] = j < n;
        d[k] = has[k] ? dst[e0 + j] : 0;
    }
    #pragma unroll
    for (int k = 0; k < 8; ++k)
        if (has[k]) atomicAdd(&h[d[k] >> 8], 1);
    __syncthreads();
    for (int i = t; i < NB; i += 512) {
        int c = h[i];
        bb[i] = (c > 0) ? (i * CAP + atomicAdd(&bucketCur[i], c)) : 0;
        h[i] = 0;  // reuse as cursor
    }
    __syncthreads();
    int s[8];
    #pragma unroll
    for (int k = 0; k < 8; ++k) {
        int j = t + k * 512;
        s[k] = has[k] ? src[e0 + j] : 0;
    }
    #pragma unroll
    for (int k = 0; k < 8; ++k)
        if (has[k]) {
            int b = d[k] >> 8;
            int pos = bb[b] + atomicAdd(&h[b], 1);
            ebuf[pos] = s[k] | ((d[k] & (BNODES - 1)) << PACK_SHIFT);
        }
}

// One block per bucket: node degrees (LDS) -> dis + rowptr2{start,end} (region space),
// then order the bucket's region into srcs (also region space).
__global__ __launch_bounds__(512) void bin_fill_kernel(const int* __restrict__ ebuf,
                                                       const int* __restrict__ bucketCnt,
                                                       int2* __restrict__ rowptr2,
                                                       float* __restrict__ dis,
                                                       int* __restrict__ srcs,
                                                       int CAP, int N) {
    __shared__ int cntL[BNODES];
    __shared__ int rb[BNODES];
    int b = blockIdx.x;
    int t = threadIdx.x;
    int base = b * BNODES;
    int cnt = bucketCnt[b];
    int s0 = b * CAP, s1 = s0 + cnt;
    if (t < BNODES) cntL[t] = 0;
    __syncthreads();
    for (int i = s0 + t; i < s1; i += 512)
        atomicAdd(&cntL[((unsigned)ebuf[i]) >> PACK_SHIFT], 1);
    __syncthreads();
    int myc = 0;
    if (t < BNODES) {
        myc = cntL[t];
        if (base + t < N) dis[base + t] = rsqrtf((float)myc + 1.0f);
        rb[t] = myc;
    }
    __syncthreads();
    #pragma unroll
    for (int off = 1; off < BNODES; off <<= 1) {
        int add = (t < BNODES && t >= off) ? rb[t - off] : 0;
        __syncthreads();
        if (t < BNODES) rb[t] += add;
        __syncthreads();
    }
    if (t < BNODES) {
        int start = s0 + rb[t] - myc;
        if (base + t < N) rowptr2[base + t] = make_int2(start, start + myc);
        rb[t] = start;
        cntL[t] = 0;  // reuse as cursor
    }
    __syncthreads();
    const int mask = (1 << PACK_SHIFT) - 1;
    for (int i = s0 + t; i < s1; i += 512) {
        int w = ebuf[i];
        int local = ((unsigned)w) >> PACK_SHIFT;
        int pos = rb[local] + atomicAdd(&cntL[local], 1);
        srcs[pos] = w & mask;
    }
}

// ---------------- tiled GEMM ----------------
// Y[M,64] = X[M,K] @ W[K,64]; XT/YT = ushort (bf16) or float.
template<int K, bool SCALE, typename XT, typename YT>
__global__ __launch_bounds__(256, 4) void gemm_tiled(const XT* __restrict__ X,
                                                     const float* __restrict__ W,
                                                     const float* __restrict__ dis,
                                                     YT* __restrict__ Y, int M) {
    __shared__ float Ws[32 * 64];   // current K-chunk of W
    __shared__ float Xs[32 * 68];   // transposed X chunk [k][row], pitch 68
    const int t = threadIdx.x;

    const int r0 = blockIdx.x * 64;
    const int wave = t >> 6;
    const int lane = t & 63;
    const int tr = lane & 15;
    const int tc = (lane >> 4) + wave * 4;

    float acc[4][4] = {};

    #pragma unroll 1
    for (int kc = 0; kc < K; kc += 32) {
        __syncthreads();
        #pragma unroll
        for (int it = 0; it < 2; ++it) {
            int i = it * 256 + t;
            ((float4*)Ws)[i] = ((const float4*)(W + (size_t)kc * 64))[i];
        }
        #pragma unroll
        for (int it = 0; it < 2; ++it) {
            int i = it * 256 + t;
            int row = i & 63;
            int kq = i >> 6;           // 0..7
            int gr = r0 + row;
            if (gr >= M) gr = M - 1;
            float v0, v1, v2, v3;
            if constexpr (sizeof(XT) == 2) {
                uint2 v = *(const uint2*)((const unsigned short*)X +
                                          (size_t)gr * K + kc + kq * 4);
                v0 = bf2f_lo(v.x); v1 = bf2f_hi(v.x);
                v2 = bf2f_lo(v.y); v3 = bf2f_hi(v.y);
            } else {
                float4 v = *(const float4*)((const float*)X + (size_t)gr * K + kc + kq * 4);
                v0 = v.x; v1 = v.y; v2 = v.z; v3 = v.w;
            }
            Xs[(kq * 4 + 0) * 68 + row] = v0;
            Xs[(kq * 4 + 1) * 68 + row] = v1;
            Xs[(kq * 4 + 2) * 68 + row] = v2;
            Xs[(kq * 4 + 3) * 68 + row] = v3;
        }
        __syncthreads();
        #pragma unroll
        for (int kk = 0; kk < 32; ++kk) {
            float4 xv = *(const float4*)(Xs + kk * 68 + tr * 4);
            float4 wv = *(const float4*)(Ws + kk * 64 + tc * 4);
            acc[0][0] = fmaf(xv.x, wv.x, acc[0][0]);
            acc[0][1] = fmaf(xv.x, wv.y, acc[0][1]);
            acc[0][2] = fmaf(xv.x, wv.z, acc[0][2]);
            acc[0][3] = fmaf(xv.x, wv.w, acc[0][3]);
            acc[1][0] = fmaf(xv.y, wv.x, acc[1][0]);
            acc[1][1] = fmaf(xv.y, wv.y, acc[1][1]);
            acc[1][2] = fmaf(xv.y, wv.z, acc[1][2]);
            acc[1][3] = fmaf(xv.y, wv.w, acc[1][3]);
            acc[2][0] = fmaf(xv.z, wv.x, acc[2][0]);
            acc[2][1] = fmaf(xv.z, wv.y, acc[2][1]);
            acc[2][2] = fmaf(xv.z, wv.z, acc[2][2]);
            acc[2][3] = fmaf(xv.z, wv.w, acc[2][3]);
            acc[3][0] = fmaf(xv.w, wv.x, acc[3][0]);
            acc[3][1] = fmaf(xv.w, wv.y, acc[3][1]);
            acc[3][2] = fmaf(xv.w, wv.z, acc[3][2]);
            acc[3][3] = fmaf(xv.w, wv.w, acc[3][3]);
        }
    }

    #pragma unroll
    for (int i = 0; i < 4; ++i) {
        int row = r0 + tr * 4 + i;
        if (row < M) {
            float s = SCALE ? dis[row] : 1.0f;
            if constexpr (sizeof(YT) == 2) {
                ushort4 st;
                st.x = f2bf(acc[i][0] * s);
                st.y = f2bf(acc[i][1] * s);
                st.z = f2bf(acc[i][2] * s);
                st.w = f2bf(acc[i][3] * s);
                *(ushort4*)((unsigned short*)Y + (size_t)row * 64 + tc * 4) = st;
            } else {
                float4 st = make_float4(acc[i][0] * s, acc[i][1] * s,
                                        acc[i][2] * s, acc[i][3] * s);
                *(float4*)((float*)Y + (size_t)row * 64 + tc * 4) = st;
            }
        }
    }
}

// ---------------- pull aggregate ----------------
// 2 nodes/wave; per node: 8 lanes x uint4 (8 bf16 feats) x 4 edge-slots.
// Lock-step masked loop; slot partials combined (shfl 16,8) pre-ReLU.
// HEAD=false: out = bf16 h1 [N][64]. HEAD=true: s01[node] head dots.
template<bool HEAD>
__global__ __launch_bounds__(256) void pull4_kernel(const unsigned* __restrict__ hpre2,
                                                    const int2* __restrict__ rowptr2,
                                                    const int* __restrict__ srcs,
                                                    const float* __restrict__ dis,
                                                    const float* __restrict__ b,
                                                    const float* __restrict__ Wh,
                                                    unsigned* __restrict__ out,
                                                    float2* __restrict__ s01, int N) {
    int tid = threadIdx.x;
    int lane = tid & 63;
    int half = lane >> 5;          // which node of the wave's pair
    int sub = lane & 31;
    int eo = sub >> 3;             // edge slot 0..3
    int l = sub & 7;               // feature octet: feats 8l..8l+7
    int node = blockIdx.x * 8 + (tid >> 6) * 2 + half;
    bool valid = node < N;
    int nc = valid ? node : N - 1;
    int2 se = rowptr2[nc];
    int i0 = se.x;
    int end = valid ? se.y : i0;
    int fb = (i0 < end) ? i0 : 0;  // safe fallback edge index

    const uint4* hp4 = (const uint4*)hpre2;   // row = 8 x uint4
    uint4 sv = hp4[(size_t)nc * 8 + l];       // self loop (eo==0 lanes keep it)
    float a0 = eo ? 0.f : bf2f_lo(sv.x);
    float a1 = eo ? 0.f : bf2f_hi(sv.x);
    float a2 = eo ? 0.f : bf2f_lo(sv.y);
    float a3 = eo ? 0.f : bf2f_hi(sv.y);
    float a4 = eo ? 0.f : bf2f_lo(sv.z);
    float a5 = eo ? 0.f : bf2f_hi(sv.z);
    float a6 = eo ? 0.f : bf2f_lo(sv.w);
    float a7 = eo ? 0.f : bf2f_hi(sv.w);

    int i = i0 + eo;
    while (__any(i < end)) {
        #pragma unroll
        for (int k = 0; k < 4; ++k) {        // 4 steps x 4 slots = 16 edges/node/iter
            int idx = i + 4 * k;
            bool m = idx < end;
            int s = srcs[m ? idx : fb];
            uint4 v = hp4[(size_t)s * 8 + l];
            a0 += m ? bf2f_lo(v.x) : 0.f;
            a1 += m ? bf2f_hi(v.x) : 0.f;
            a2 += m ? bf2f_lo(v.y) : 0.f;
            a3 += m ? bf2f_hi(v.y) : 0.f;
            a4 += m ? bf2f_lo(v.z) : 0.f;
            a5 += m ? bf2f_hi(v.z) : 0.f;
            a6 += m ? bf2f_lo(v.w) : 0.f;
            a7 += m ? bf2f_hi(v.w) : 0.f;
        }
        i += 16;
    }

    // combine 4 edge-slot partials -> lanes eo==0
    a0 += __shfl_down(a0, 16, 32); a1 += __shfl_down(a1, 16, 32);
    a2 += __shfl_down(a2, 16, 32); a3 += __shfl_down(a3, 16, 32);
    a4 += __shfl_down(a4, 16, 32); a5 += __shfl_down(a5, 16, 32);
    a6 += __shfl_down(a6, 16, 32); a7 += __shfl_down(a7, 16, 32);
    a0 += __shfl_down(a0, 8, 32);  a1 += __shfl_down(a1, 8, 32);
    a2 += __shfl_down(a2, 8, 32);  a3 += __shfl_down(a3, 8, 32);
    a4 += __shfl_down(a4, 8, 32);  a5 += __shfl_down(a5, 8, 32);
    a6 += __shfl_down(a6, 8, 32);  a7 += __shfl_down(a7, 8, 32);

    float d = dis[nc];
    float4 bL = ((const float4*)b)[2 * l];
    float4 bH = ((const float4*)b)[2 * l + 1];
    float o0 = fmaf(a0, d, bL.x), o1 = fmaf(a1, d, bL.y);
    float o2 = fmaf(a2, d, bL.z), o3 = fmaf(a3, d, bL.w);
    float o4 = fmaf(a4, d, bH.x), o5 = fmaf(a5, d, bH.y);
    float o6 = fmaf(a6, d, bH.z), o7 = fmaf(a7, d, bH.w);
    o0 = o0 > 0.f ? o0 : 0.f; o1 = o1 > 0.f ? o1 : 0.f;
    o2 = o2 > 0.f ? o2 : 0.f; o3 = o3 > 0.f ? o3 : 0.f;
    o4 = o4 > 0.f ? o4 : 0.f; o5 = o5 > 0.f ? o5 : 0.f;
    o6 = o6 > 0.f ? o6 : 0.f; o7 = o7 > 0.f ? o7 : 0.f;

    if (HEAD) {
        float4 wa = ((const float4*)Wh)[2 * l];
        float4 wb = ((const float4*)Wh)[2 * l + 1];
        float4 wc = ((const float4*)(Wh + 64))[2 * l];
        float4 wd = ((const float4*)(Wh + 64))[2 * l + 1];
        float p0 = o0 * wa.x + o1 * wa.y + o2 * wa.z + o3 * wa.w
                 + o4 * wb.x + o5 * wb.y + o6 * wb.z + o7 * wb.w;
        float p1 = o0 * wc.x + o1 * wc.y + o2 * wc.z + o3 * wc.w
                 + o4 * wd.x + o5 * wd.y + o6 * wd.z + o7 * wd.w;
        #pragma unroll
        for (int off = 4; off > 0; off >>= 1) {
            p0 += __shfl_down(p0, off, 8);
            p1 += __shfl_down(p1, off, 8);
        }
        if (valid && sub == 0) s01[node] = make_float2(p0, p1);
    } else {
        if (valid && eo == 0) {
            uint4 st;
            st.x = (unsigned)f2bf(o0) | ((unsigned)f2bf(o1) << 16);
            st.y = (unsigned)f2bf(o2) | ((unsigned)f2bf(o3) << 16);
            st.z = (unsigned)f2bf(o4) | ((unsigned)f2bf(o5) << 16);
            st.w = (unsigned)f2bf(o6) | ((unsigned)f2bf(o7) << 16);
            ((uint4*)out)[(size_t)node * 8 + l] = st;
        }
    }
}

// out[p] = s01[p0].x + s01[p1].y + bh  (s01 is ~800KB -> L2-resident gathers)
__global__ void pair_kernel(const float2* __restrict__ s01, const int2* __restrict__ pairs,
                            const float* __restrict__ bh, float* __restrict__ out, int P) {
    int p = blockIdx.x * blockDim.x + threadIdx.x;
    if (p < P) {
        int2 pr = pairs[p];
        out[p] = s01[pr.x].x + s01[pr.y].y + bh[0];
    }
}

// ---------------- fallback (atomic push, full fp32) ----------------
__global__ void degf_kernel(const int* __restrict__ dst, float* __restrict__ deg, int E) {
    int e = blockIdx.x * blockDim.x + threadIdx.x;
    if (e < E) atomicAdd(&deg[dst[e]], 1.0f);
}
__global__ void rsqrtf_kernel(float* deg, int N) {
    int i = blockIdx.x * blockDim.x + threadIdx.x;
    if (i < N) deg[i] = rsqrtf(deg[i] + 1.0f);
}
__global__ void scatter_kernel(const float* __restrict__ h, const int* __restrict__ src,
                               const int* __restrict__ dst, const float* __restrict__ dis,
                               float* __restrict__ agg, int E, int N) {
    long long idx = (long long)blockIdx.x * blockDim.x + threadIdx.x;
    int e = (int)(idx >> 6);
    int f = (int)(idx & 63);
    if (e >= E + N) return;
    int s, d;
    if (e < E) { s = src[e]; d = dst[e]; } else { s = e - E; d = s; }
    float norm = dis[s] * dis[d];
    atomicAdd(&agg[(size_t)d * 64 + f], h[(size_t)s * 64 + f] * norm);
}
__global__ void bias_relu_kernel(float* __restrict__ buf, const float* __restrict__ b,
                                 long long total) {
    long long i = (long long)blockIdx.x * blockDim.x + threadIdx.x;
    if (i < total) {
        float v = buf[i] + b[(int)(i & 63)];
        buf[i] = v > 0.f ? v : 0.f;
    }
}
__global__ void head_kernel(const float* __restrict__ h, const int* __restrict__ pairs,
                            const float* __restrict__ Wh, const float* __restrict__ bh,
                            float* __restrict__ out, int P) {
    long long idx = (long long)blockIdx.x * blockDim.x + threadIdx.x;
    int p = (int)(idx >> 6);
    int lane = threadIdx.x & 63;
    if (p >= P) return;
    int p0 = pairs[2 * (size_t)p];
    int p1 = pairs[2 * (size_t)p + 1];
    float v = h[(size_t)p0 * 64 + lane] * Wh[lane]
            + h[(size_t)p1 * 64 + lane] * Wh[64 + lane];
    #pragma unroll
    for (int off = 32; off > 0; off >>= 1) v += __shfl_down(v, off);
    if (lane == 0) out[p] = v + bh[0];
}

extern "C" void kernel_launch(void* const* d_in, const int* in_sizes, int n_in,
                              void* d_out, int out_size, void* d_ws, size_t ws_size,
                              hipStream_t stream) {
    const float* x     = (const float*)d_in[0];
    const int*   ei    = (const int*)d_in[1];   // [2,E]: row0=src, row1=dst
    const int*   pairs = (const int*)d_in[3];   // [P,2]
    const float* W1    = (const float*)d_in[4];
    const float* b1    = (const float*)d_in[5];
    const float* W2    = (const float*)d_in[6];
    const float* b2    = (const float*)d_in[7];
    const float* Wh    = (const float*)d_in[8];
    const float* bh    = (const float*)d_in[9];

    const int N = in_sizes[0] / 128;
    const int E = in_sizes[1] / 2;
    const int P = in_sizes[3] / 2;
    const int* srcArr = ei;
    const int* dstArr = ei + E;

    const size_t feat_total = (size_t)N * 64;
    const int NB = (N + BNODES - 1) / BNODES;      // dst buckets
    const int tileBlocks = (E + TILE - 1) / TILE;  // edge tiles
    const int gemm_blocks = (N + 63) / 64;
    const int pull_blocks = (N + 7) / 8;

    auto align512 = [](size_t v) { return (v + 511) & ~(size_t)511; };

    char* ws = (char*)d_ws;
    size_t off = 0;
    float*  dis     = (float*) (ws + off); off += align512((size_t)N * 4);
    int2*   rowptr2 = (int2*)  (ws + off); off += align512((size_t)N * 8);
    int*    bucketCur = (int*) (ws + off); off += align512((size_t)NB * 4);
    float2* s01     = (float2*)(ws + off); off += align512((size_t)N * 8);
    // bufA slot: ebuf (bucket regions) early, then bf16 hpre [N][64]
    size_t bufA_bytes = align512((size_t)E * 4 > feat_total * 2 ? (size_t)E * 4
                                                                : feat_total * 2);
    unsigned short* bufA = (unsigned short*)(ws + off); off += bufA_bytes;
    int*    srcs    = (int*)   (ws + off); off += bufA_bytes;   // region-space srcs
    float*  bufB    = (float*) (ws + off); off += align512(feat_total * 4);  // bf16 h1 (csr path) / fp32 (fallback)
    int*    ebuf    = (int*)bufA;  // aliased: consumed by bin_fill before gemm1 writes bufA

    const int CAP = (int)(bufA_bytes / ((size_t)4 * NB));       // slots per bucket
    const int avgB = (E + NB - 1) / NB;                         // expected bucket fill
    const bool csr_ok = (off <= ws_size) && (NB <= 1024) && (N <= (1 << PACK_SHIFT)) &&
                        (CAP >= avgB + (avgB >> 2) + 1024);     // >25%+1024 slack

    if (csr_ok) {
        // ---- CSR build (single edge pass, region-space offsets) ----
        zero1_kernel<<<1, 1024, 0, stream>>>(bucketCur, NB);
        block_scatter<<<tileBlocks, 512, 0, stream>>>(srcArr, dstArr, bucketCur,
                                                      ebuf, NB, CAP, E);
        bin_fill_kernel<<<NB, 512, 0, stream>>>(ebuf, bucketCur, rowptr2, dis, srcs,
                                                CAP, N);

        // ---- layer 1: hpre1(bf16) = (x@W1)*dis ; h1(bf16) = relu(dis*pull + b1) ----
        gemm_tiled<128, true, float, unsigned short><<<gemm_blocks, THREADS, 0, stream>>>(
            x, W1, dis, bufA, N);
        pull4_kernel<false><<<pull_blocks, THREADS, 0, stream>>>(
            (const unsigned*)bufA, rowptr2, srcs, dis, b1, nullptr,
            (unsigned*)bufB, nullptr, N);

        // ---- layer 2 (bf16 in/out) + head dots fused ----
        gemm_tiled<64, true, unsigned short, unsigned short><<<gemm_blocks, THREADS, 0, stream>>>(
            (const unsigned short*)bufB, W2, dis, bufA, N);
        pull4_kernel<true><<<pull_blocks, THREADS, 0, stream>>>(
            (const unsigned*)bufA, rowptr2, srcs, dis, b2, Wh, nullptr, s01, N);

        // ---- pair gather ----
        pair_kernel<<<(P + THREADS - 1) / THREADS, THREADS, 0, stream>>>(
            s01, (const int2*)pairs, bh, (float*)d_out, P);
    } else {
        // ---- fallback: atomic push path, fp32 ----
        size_t o2 = 0;
        float* deg  = (float*)(ws + o2); o2 += align512((size_t)N * 4);
        float* bA   = (float*)(ws + o2); o2 += align512(feat_total * 4);
        float* bB   = (float*)(ws + o2);
        const size_t edge_threads = (size_t)(E + N) * 64;
        const int eblocks = (E + THREADS - 1) / THREADS;

        hipMemsetAsync(deg, 0, (size_t)N * 4, stream);
        degf_kernel<<<eblocks, THREADS, 0, stream>>>(dstArr, deg, E);
        rsqrtf_kernel<<<(N + THREADS - 1) / THREADS, THREADS, 0, stream>>>(deg, N);

        gemm_tiled<128, false, float, float><<<gemm_blocks, THREADS, 0, stream>>>(
            x, W1, deg, bA, N);
        hipMemsetAsync(bB, 0, feat_total * 4, stream);
        scatter_kernel<<<(unsigned)((edge_threads + THREADS - 1) / THREADS), THREADS, 0, stream>>>(
            bA, srcArr, dstArr, deg, bB, E, N);
        bias_relu_kernel<<<(unsigned)((feat_total + THREADS - 1) / THREADS), THREADS, 0, stream>>>(
            bB, b1, (long long)feat_total);

        gemm_tiled<64, false, float, float><<<gemm_blocks, THREADS, 0, stream>>>(
            bB, W2, deg, bA, N);
        hipMemsetAsync(bB, 0, feat_total * 4, stream);
        scatter_kernel<<<(unsigned)((edge_threads + THREADS - 1) / THREADS), THREADS, 0, stream>>>(
            bA, srcArr, dstArr, deg, bB, E, N);
        bias_relu_kernel<<<(unsigned)((feat_total + THREADS - 1) / THREADS), THREADS, 0, stream>>>(
            bB, b2, (long long)feat_total);

        head_kernel<<<(unsigned)(((size_t)P * 64 + THREADS - 1) / THREADS), THREADS, 0, stream>>>(
            bB, pairs, Wh, bh, (float*)d_out, P);
    }
}